// Round 1
// baseline (382.822 us; speedup 1.0000x reference)
//
#include <hip/hip_runtime.h>
#include <hip/hip_bf16.h>

// Problem constants (AriaExperts): tokens=2048, hidden=1024, inter=2048, E=8, topk=2
constexpr int T = 2048;
constexpr int H = 1024;
constexpr int I = 2048;
constexpr int N2 = 2 * I;      // fc1 weight cols (proj|gate)
constexpr int RCAP = 5120;     // padded row capacity
constexpr int MAXT = 40;       // max 128-row tiles

// ws int-offset map (ints)
constexpr int WS_OFF = 16;                 // [16,25) expert row offsets (padded)
constexpr int WS_TEXP = 32;                // [32,72) tile -> expert
constexpr int WS_TOPKP = 4256;             // [4256,8352) token scales (float)
constexpr int WS_ROWTOK = 8352;            // [8352,13472) row -> token
constexpr int WS_TOKROW = 13472;           // [13472,17568) token -> 2 rows
// ws byte offsets
constexpr size_t WSB_ZROW = 114688;        // bf16 zero row, H elements
constexpr size_t WSB_HSB  = 131072;        // bf16 hidden_states [T][H] (4 MB)
constexpr size_t WSB_ACT  = 8u << 20;      // bf16 act [RCAP][I] (20 MB)
constexpr size_t WSB_PW1  = 32u << 20;     // packed bf16 w1 (64 MB); reused as eo[2][RCAP][H] fp32 (40 MB)
constexpr size_t WSB_PW2  = 96u << 20;     // packed bf16 w2 (32 MB) -> 128 MB ws

// prep grid: LDS-transpose tiles (streaming reads AND writes)
constexpr int W1T_BLKS = 8 * 32 * 8;       // e * k0i * colslab(512)  = 2048
constexpr int W2T_BLKS = 8 * 64 * 2;       // e * k0i * colslab(512)  = 1024
constexpr int HSB_BLKS = T * H / 2048;     // 1024
constexpr int FC1_BLKS = 32 * MAXT;        // 1280

typedef __attribute__((ext_vector_type(4))) float f32x4;
typedef __attribute__((ext_vector_type(8))) short s16x8;

__device__ __forceinline__ short f2bf(float f) {
    unsigned u = __float_as_uint(f);
    u += 0x7FFFu + ((u >> 16) & 1u);   // round-to-nearest-even
    return (short)(u >> 16);
}

#define MFMA16(a, b, c) __builtin_amdgcn_mfma_f32_16x16x32_bf16(a, b, c, 0, 0, 0)

__device__ __forceinline__ void gl2lds16(const void* g, void* l) {
    __builtin_amdgcn_global_load_lds(
        (const __attribute__((address_space(1))) void*)g,
        (__attribute__((address_space(3))) void*)l, 16, 0, 0);
}

// ---------------- routing: top2+softmax, histogram, prefix, scatter, inits (1 block) ----------------
__global__ __launch_bounds__(256) void routing_kernel(const float* __restrict__ logits,
                                                      int* __restrict__ wsi,
                                                      float* __restrict__ wsf) {
    __shared__ int cnt[8], base[9], fill[8];
    const int t = threadIdx.x;
    if (t < 8) { cnt[t] = 0; fill[t] = 0; }
    for (int r = t; r < RCAP; r += 256) wsi[WS_ROWTOK + r] = -1;
    unsigned short* zr = (unsigned short*)((char*)wsi + WSB_ZROW);
    for (int i = t; i < H; i += 256) zr[i] = 0;
    __syncthreads();

    int e0a[8], e1a[8];
    #pragma unroll
    for (int j = 0; j < 8; j++) {
        int tok = t * 8 + j;
        const float* l = logits + tok * 8;
        float v0 = -1e30f; int i0 = 0;
        #pragma unroll
        for (int i = 0; i < 8; i++) { float v = l[i]; if (v > v0) { v0 = v; i0 = i; } }
        float v1 = -1e30f; int i1 = 0;
        #pragma unroll
        for (int i = 0; i < 8; i++) { if (i == i0) continue; float v = l[i]; if (v > v1) { v1 = v; i1 = i; } }
        float ex = __expf(v1 - v0);
        float inv = 1.f / (1.f + ex);
        wsf[WS_TOPKP + tok * 2] = inv;
        wsf[WS_TOPKP + tok * 2 + 1] = ex * inv;
        e0a[j] = i0; e1a[j] = i1;
        atomicAdd(&cnt[i0], 1);
        atomicAdd(&cnt[i1], 1);
    }
    __syncthreads();
    if (t == 0) {
        int acc = 0;
        for (int e = 0; e < 8; e++) { base[e] = acc; acc += (cnt[e] + 127) & ~127; }
        base[8] = acc;
        for (int e = 0; e < 9; e++) wsi[WS_OFF + e] = base[e];
    }
    __syncthreads();
    for (int tt = t; tt < MAXT; tt += 256) {
        int rb = tt * 128, ex = 0;
        for (int e = 0; e < 8; e++)
            if (rb >= base[e] && rb < base[e + 1]) ex = e;
        wsi[WS_TEXP + tt] = ex;
    }
    #pragma unroll
    for (int j = 0; j < 8; j++) {
        int tok = t * 8 + j;
        int ee[2] = {e0a[j], e1a[j]};
        #pragma unroll
        for (int k = 0; k < 2; k++) {
            int e = ee[k];
            int slot = atomicAdd(&fill[e], 1);
            int r = base[e] + slot;
            wsi[WS_ROWTOK + r] = tok;
            wsi[WS_TOKROW + tok * 2 + k] = r;
        }
    }
}

// ---------------- prep: pack w1 (interleaved 32p|32g), pack w2, hs->bf16 ----------------
// LDS-staged transpose: both global read and global write are streaming.
// Phase 1: read [k:32][c:512] fp32 tile (2 KB contiguous per wave), cvt bf16,
//          store row-major to LDS (ds_write_b128, conflict-free).
// Phase 2: per output 16B chunk gather 8 k's from LDS (stride 1 KB -> 2 lanes/bank,
//          free), write packed chunks (512B-1KB contiguous runs per wave).
// pw1 layout (unchanged): block b=((e*32+ct)*32)+k0i holds [kg:4][n:128][kk:8],
//   k = k0i*32+kg*8+kk, col = (sub&1 ? I : 0) + ct*64 + (sub>>1)*32 + (n&31), sub=n>>5
// pw2 layout (unchanged): block b=((e*8+ht)*64)+k0i holds [kg:4][n:128][kk:8], col=ht*128+n
__global__ __launch_bounds__(256) void prep_kernel(
    const float* __restrict__ w1, unsigned short* __restrict__ pw1,
    const float* __restrict__ w2, unsigned short* __restrict__ pw2,
    const float* __restrict__ hs, unsigned short* __restrict__ hsb) {
    __shared__ __align__(16) unsigned short L[32 * 512];
    const int t = threadIdx.x;
    if (blockIdx.x < W1T_BLKS) {
        int b = blockIdx.x;
        int cs = b & 7, k0i = (b >> 3) & 31, e = b >> 8;
        const float* src = w1 + (size_t)e * H * N2 + (size_t)(k0i * 32) * N2 + cs * 512;
        #pragma unroll
        for (int i = 0; i < 8; i++) {
            int c = t + i * 256;                 // 2048 chunks x 8 elem
            int row = c >> 6, col8 = (c & 63) * 8;
            const float* sp = src + (size_t)row * N2 + col8;
            f32x4 a = *(const f32x4*)sp;
            f32x4 bb = *(const f32x4*)(sp + 4);
            s16x8 s = {f2bf(a[0]), f2bf(a[1]), f2bf(a[2]), f2bf(a[3]),
                       f2bf(bb[0]), f2bf(bb[1]), f2bf(bb[2]), f2bf(bb[3])};
            *(s16x8*)&L[c * 8] = s;
        }
        __syncthreads();
        int gate = cs >> 2;                      // slabs 4..7 are the gate half
        int ctbase = (cs & 3) * 8;
        unsigned short* dstb = pw1 + (size_t)(e * 1024 + k0i) * 4096;
        #pragma unroll
        for (int i = 0; i < 8; i++) {
            int cidx = t + i * 256;
            int within = cidx & 31, nhalf = (cidx >> 5) & 1;
            int kg = (cidx >> 6) & 3, ctp = cidx >> 8;
            int x = ctp * 64 + nhalf * 32 + within;          // LDS col
            int n = gate * 32 + nhalf * 64 + within;         // packed n
            s16x8 s;
            #pragma unroll
            for (int kk = 0; kk < 8; kk++) s[kk] = (short)L[(kg * 8 + kk) * 512 + x];
            int ct = ctbase + ctp;
            *(s16x8*)(dstb + (size_t)ct * 32 * 4096 + (kg * 128 + n) * 8) = s;
        }
    } else if (blockIdx.x < W1T_BLKS + W2T_BLKS) {
        int b = blockIdx.x - W1T_BLKS;
        int cs = b & 1, k0i = (b >> 1) & 63, e = b >> 7;
        const float* src = w2 + (size_t)e * I * H + (size_t)(k0i * 32) * H + cs * 512;
        #pragma unroll
        for (int i = 0; i < 8; i++) {
            int c = t + i * 256;
            int row = c >> 6, col8 = (c & 63) * 8;
            const float* sp = src + (size_t)row * H + col8;
            f32x4 a = *(const f32x4*)sp;
            f32x4 bb = *(const f32x4*)(sp + 4);
            s16x8 s = {f2bf(a[0]), f2bf(a[1]), f2bf(a[2]), f2bf(a[3]),
                       f2bf(bb[0]), f2bf(bb[1]), f2bf(bb[2]), f2bf(bb[3])};
            *(s16x8*)&L[c * 8] = s;
        }
        __syncthreads();
        unsigned short* dstb = pw2 + (size_t)(e * 512 + k0i) * 4096;
        #pragma unroll
        for (int i = 0; i < 8; i++) {
            int cidx = t + i * 256;
            int n = cidx & 127, kg = (cidx >> 7) & 3, htp = cidx >> 9;
            int x = htp * 128 + n;
            s16x8 s;
            #pragma unroll
            for (int kk = 0; kk < 8; kk++) s[kk] = (short)L[(kg * 8 + kk) * 512 + x];
            int ht = cs * 4 + htp;
            *(s16x8*)(dstb + (size_t)ht * 64 * 4096 + (kg * 128 + n) * 8) = s;
        }
    } else {
        int i = ((blockIdx.x - W1T_BLKS - W2T_BLKS) * 256 + t) * 8;
        f32x4 a = *(const f32x4*)(hs + i);
        f32x4 b = *(const f32x4*)(hs + i + 4);
        s16x8 s = {f2bf(a[0]), f2bf(a[1]), f2bf(a[2]), f2bf(a[3]),
                   f2bf(b[0]), f2bf(b[1]), f2bf(b[2]), f2bf(b[3])};
        *(s16x8*)(hsb + i) = s;
    }
}

// ---------------- fc1 (128x128, BK=32) + SwiGLU ----------------
__global__ __launch_bounds__(256, 2) void fc1_kernel(
    const unsigned short* __restrict__ hsb, const unsigned short* __restrict__ pw1,
    const int* __restrict__ wsi, const unsigned short* __restrict__ zrow,
    unsigned short* __restrict__ act) {
    __shared__ __align__(16) unsigned short Al[512 * 8];    // [kg:4][m:128][8]
    __shared__ __align__(16) unsigned short Bl[512 * 8];    // [kg:4][n:128][8]
    const int t = threadIdx.x;
    const int ct = blockIdx.x & 31, rt = blockIdx.x >> 5;
    const int rowb = rt * 128;
    if (rowb >= wsi[WS_OFF + 8]) return;
    const int e = wsi[WS_TEXP + rt];
    const unsigned short* pb = pw1 + (size_t)((e * 32 + ct) * 32) * 4096;

    const int m = t & 127;
    const int tok = wsi[WS_ROWTOK + rowb + m];
    const unsigned short* rp = (tok >= 0) ? (hsb + (size_t)tok * H) : zrow;
    const int kga = t >> 7;

    const int lane = t & 63, w = t >> 6, wr = w >> 1, wc = w & 1;
    const int q = lane >> 4, l16 = lane & 15;

    f32x4 zero = {0.f, 0.f, 0.f, 0.f};
    f32x4 acc[4][4];
    #pragma unroll
    for (int mi = 0; mi < 4; mi++)
        #pragma unroll
        for (int ni = 0; ni < 4; ni++) acc[mi][ni] = zero;

    for (int k0i = 0; k0i < 32; k0i++) {
        const int k0 = k0i * 32;
        gl2lds16(rp + k0 + kga * 8, &Al[t * 8]);
        gl2lds16(rp + k0 + (kga + 2) * 8, &Al[(t + 256) * 8]);
        const unsigned short* ps = pb + (size_t)k0i * 4096;
        gl2lds16(ps + t * 8, &Bl[t * 8]);
        gl2lds16(ps + (t + 256) * 8, &Bl[(t + 256) * 8]);
        __syncthreads();

        s16x8 af[4], bf[4];
        #pragma unroll
        for (int mi = 0; mi < 4; mi++)
            af[mi] = *(const s16x8*)&Al[(q * 128 + wr * 64 + mi * 16 + l16) * 8];
        #pragma unroll
        for (int ni = 0; ni < 4; ni++)
            bf[ni] = *(const s16x8*)&Bl[(q * 128 + wc * 64 + ni * 16 + l16) * 8];
        #pragma unroll
        for (int mi = 0; mi < 4; mi++)
            #pragma unroll
            for (int ni = 0; ni < 4; ni++)
                acc[mi][ni] = MFMA16(af[mi], bf[ni], acc[mi][ni]);
        __syncthreads();
    }

    // epilogue: wave cols = 32 proj + 32 gate (ni 0,1 = proj; ni 2,3 = matching gate)
    #pragma unroll
    for (int mi = 0; mi < 4; mi++)
        #pragma unroll
        for (int r = 0; r < 4; r++) {
            int row = rowb + wr * 64 + mi * 16 + q * 4 + r;
            #pragma unroll
            for (int ni = 0; ni < 2; ni++) {
                int col = ct * 64 + wc * 32 + ni * 16 + l16;
                float p = acc[mi][ni][r], g = acc[mi][ni + 2][r];
                float val = p * g / (1.f + __expf(-p));
                act[(size_t)row * I + col] = (unsigned short)f2bf(val);
            }
        }
}

// ---------------- fc2 (128x128, BK=32, K-split x2) -> eo partials, no atomics ----------------
__global__ __launch_bounds__(256, 2) void fc2_kernel(
    const unsigned short* __restrict__ act, const unsigned short* __restrict__ pw2,
    const int* __restrict__ wsi, float* __restrict__ eo) {
    __shared__ __align__(16) unsigned short Al[512 * 8];
    __shared__ __align__(16) unsigned short Bl[512 * 8];
    const int t = threadIdx.x;
    const int ht = blockIdx.x, rt = blockIdx.y, ks = blockIdx.z;
    const int rowb = rt * 128;
    if (rowb >= wsi[WS_OFF + 8]) return;
    const int e = wsi[WS_TEXP + rt];
    const unsigned short* pb = pw2 + (size_t)((e * 8 + ht) * 64) * 4096;

    const int m = t & 127;
    const unsigned short* rp = act + (size_t)(rowb + m) * I;
    const int kga = t >> 7;

    const int lane = t & 63, w = t >> 6, wr = w >> 1, wc = w & 1;
    const int q = lane >> 4, l16 = lane & 15;

    f32x4 zero = {0.f, 0.f, 0.f, 0.f};
    f32x4 acc[4][4];
    #pragma unroll
    for (int mi = 0; mi < 4; mi++)
        #pragma unroll
        for (int ni = 0; ni < 4; ni++) acc[mi][ni] = zero;

    for (int k0i = ks * 32; k0i < ks * 32 + 32; k0i++) {
        const int k0 = k0i * 32;
        gl2lds16(rp + k0 + kga * 8, &Al[t * 8]);
        gl2lds16(rp + k0 + (kga + 2) * 8, &Al[(t + 256) * 8]);
        const unsigned short* ps = pb + (size_t)k0i * 4096;
        gl2lds16(ps + t * 8, &Bl[t * 8]);
        gl2lds16(ps + (t + 256) * 8, &Bl[(t + 256) * 8]);
        __syncthreads();

        s16x8 af[4], bf[4];
        #pragma unroll
        for (int mi = 0; mi < 4; mi++)
            af[mi] = *(const s16x8*)&Al[(q * 128 + wr * 64 + mi * 16 + l16) * 8];
        #pragma unroll
        for (int ni = 0; ni < 4; ni++)
            bf[ni] = *(const s16x8*)&Bl[(q * 128 + wc * 64 + ni * 16 + l16) * 8];
        #pragma unroll
        for (int mi = 0; mi < 4; mi++)
            #pragma unroll
            for (int ni = 0; ni < 4; ni++)
                acc[mi][ni] = MFMA16(af[mi], bf[ni], acc[mi][ni]);
        __syncthreads();
    }

    float* ed = eo + (size_t)ks * RCAP * H;
    #pragma unroll
    for (int mi = 0; mi < 4; mi++)
        #pragma unroll
        for (int r = 0; r < 4; r++) {
            int row = rowb + wr * 64 + mi * 16 + q * 4 + r;
            #pragma unroll
            for (int ni = 0; ni < 4; ni++) {
                int col = ht * 128 + wc * 64 + ni * 16 + l16;
                ed[(size_t)row * H + col] = acc[mi][ni][r];
            }
        }
}

// ---------------- combine: out[tok] = s0*(eo0[r0]+eo1[r0]) + s1*(eo0[r1]+eo1[r1]) ----------------
__global__ __launch_bounds__(256) void combine_kernel(
    const float* __restrict__ eo, const int* __restrict__ wsi,
    const float* __restrict__ wsf, float* __restrict__ out) {
    const int tok = blockIdx.x;
    const int r0 = wsi[WS_TOKROW + tok * 2], r1 = wsi[WS_TOKROW + tok * 2 + 1];
    const float s0 = wsf[WS_TOPKP + tok * 2], s1 = wsf[WS_TOPKP + tok * 2 + 1];
    const float* a0 = eo + (size_t)r0 * H;
    const float* a1 = eo + (size_t)RCAP * H + (size_t)r0 * H;
    const float* b0 = eo + (size_t)r1 * H;
    const float* b1 = eo + (size_t)RCAP * H + (size_t)r1 * H;
    const int c = threadIdx.x * 4;
    f32x4 va0 = *(const f32x4*)(a0 + c), va1 = *(const f32x4*)(a1 + c);
    f32x4 vb0 = *(const f32x4*)(b0 + c), vb1 = *(const f32x4*)(b1 + c);
    f32x4 r;
    #pragma unroll
    for (int i = 0; i < 4; i++) r[i] = s0 * (va0[i] + va1[i]) + s1 * (vb0[i] + vb1[i]);
    *(f32x4*)(out + (size_t)tok * H + c) = r;
}

extern "C" void kernel_launch(void* const* d_in, const int* in_sizes, int n_in,
                              void* d_out, int out_size, void* d_ws, size_t ws_size,
                              hipStream_t stream) {
    const float* hs     = (const float*)d_in[0];
    const float* logits = (const float*)d_in[1];
    const float* w1     = (const float*)d_in[2];
    const float* w2     = (const float*)d_in[3];
    float* out = (float*)d_out;
    int* wsi = (int*)d_ws;
    float* wsf = (float*)d_ws;
    unsigned short* zrow = (unsigned short*)((char*)d_ws + WSB_ZROW);
    unsigned short* hsb  = (unsigned short*)((char*)d_ws + WSB_HSB);
    unsigned short* act  = (unsigned short*)((char*)d_ws + WSB_ACT);
    unsigned short* pw1  = (unsigned short*)((char*)d_ws + WSB_PW1);
    unsigned short* pw2  = (unsigned short*)((char*)d_ws + WSB_PW2);
    float* eo = (float*)((char*)d_ws + WSB_PW1);   // aliases pw1 (consumed by fc1 before fc2 runs)

    routing_kernel<<<1, 256, 0, stream>>>(logits, wsi, wsf);
    prep_kernel<<<W1T_BLKS + W2T_BLKS + HSB_BLKS, 256, 0, stream>>>(w1, pw1, w2, pw2, hs, hsb);
    fc1_kernel<<<FC1_BLKS, 256, 0, stream>>>(hsb, pw1, wsi, zrow, act);
    fc2_kernel<<<dim3(8, MAXT, 2), 256, 0, stream>>>(act, pw2, wsi, eo);
    combine_kernel<<<T, 256, 0, stream>>>(eo, wsi, wsf, out);
}

// Round 2
// 372.067 us; speedup vs baseline: 1.0289x; 1.0289x over previous
//
#include <hip/hip_runtime.h>
#include <hip/hip_bf16.h>

// Problem constants (AriaExperts): tokens=2048, hidden=1024, inter=2048, E=8, topk=2
constexpr int T = 2048;
constexpr int H = 1024;
constexpr int I = 2048;
constexpr int N2 = 2 * I;      // fc1 weight cols (proj|gate)
constexpr int RCAP = 5120;     // padded row capacity
constexpr int MAXT = 40;       // max 128-row tiles

// ws int-offset map (ints)
constexpr int WS_OFF = 16;                 // [16,25) expert row offsets (padded)
constexpr int WS_TEXP = 32;                // [32,72) tile -> expert
constexpr int WS_TOPKP = 4256;             // [4256,8352) token scales (float)
constexpr int WS_ROWTOK = 8352;            // [8352,13472) row -> token
constexpr int WS_TOKROW = 13472;           // [13472,17568) token -> 2 rows
// ws byte offsets
constexpr size_t WSB_ZROW = 114688;        // bf16 zero row, H elements
constexpr size_t WSB_HSB  = 131072;        // bf16 hidden_states [T][H] (4 MB)
constexpr size_t WSB_ACT  = 8u << 20;      // bf16 act [RCAP][I] (20 MB)
constexpr size_t WSB_PW1  = 32u << 20;     // packed bf16 w1 (64 MB); reused as eo[2][RCAP][H] fp32 (40 MB)
constexpr size_t WSB_PW2  = 96u << 20;     // packed bf16 w2 (32 MB) -> 128 MB ws

// grids
constexpr int W1T_BLKS = 8 * 32 * 8;       // e * k0i * colslab(512)  = 2048
constexpr int W2T_BLKS = 8 * 64 * 2;       // e * k0i * colslab(512)  = 1024
constexpr int HSB_BLKS = T * H / 2048;     // 1024
constexpr int FC1_BLKS = 32 * MAXT;        // 1280

typedef __attribute__((ext_vector_type(4))) float f32x4;
typedef __attribute__((ext_vector_type(8))) short s16x8;

__device__ __forceinline__ short f2bf(float f) {
    unsigned u = __float_as_uint(f);
    u += 0x7FFFu + ((u >> 16) & 1u);   // round-to-nearest-even
    return (short)(u >> 16);
}

#define MFMA16(a, b, c) __builtin_amdgcn_mfma_f32_16x16x32_bf16(a, b, c, 0, 0, 0)

__device__ __forceinline__ void gl2lds16(const void* g, void* l) {
    __builtin_amdgcn_global_load_lds(
        (const __attribute__((address_space(1))) void*)g,
        (__attribute__((address_space(3))) void*)l, 16, 0, 0);
}

// ---------------- routing (block 0) + hs->bf16 (blocks 1..HSB_BLKS), independent work ----------------
__global__ __launch_bounds__(256) void routing_hs_kernel(const float* __restrict__ logits,
                                                         int* __restrict__ wsi,
                                                         float* __restrict__ wsf,
                                                         const float* __restrict__ hs,
                                                         unsigned short* __restrict__ hsb) {
    const int t = threadIdx.x;
    if (blockIdx.x > 0) {
        // hs -> bf16, streaming
        int i = (((int)blockIdx.x - 1) * 256 + t) * 8;
        f32x4 a = *(const f32x4*)(hs + i);
        f32x4 b = *(const f32x4*)(hs + i + 4);
        s16x8 s = {f2bf(a[0]), f2bf(a[1]), f2bf(a[2]), f2bf(a[3]),
                   f2bf(b[0]), f2bf(b[1]), f2bf(b[2]), f2bf(b[3])};
        *(s16x8*)(hsb + i) = s;
        return;
    }
    __shared__ int cnt[8], base[9], fill[8];
    if (t < 8) { cnt[t] = 0; fill[t] = 0; }
    for (int r = t; r < RCAP; r += 256) wsi[WS_ROWTOK + r] = -1;
    unsigned short* zr = (unsigned short*)((char*)wsi + WSB_ZROW);
    for (int i = t; i < H; i += 256) zr[i] = 0;
    __syncthreads();

    int e0a[8], e1a[8];
    #pragma unroll
    for (int j = 0; j < 8; j++) {
        int tok = t * 8 + j;
        const float* l = logits + tok * 8;
        float v0 = -1e30f; int i0 = 0;
        #pragma unroll
        for (int i = 0; i < 8; i++) { float v = l[i]; if (v > v0) { v0 = v; i0 = i; } }
        float v1 = -1e30f; int i1 = 0;
        #pragma unroll
        for (int i = 0; i < 8; i++) { if (i == i0) continue; float v = l[i]; if (v > v1) { v1 = v; i1 = i; } }
        float ex = __expf(v1 - v0);
        float inv = 1.f / (1.f + ex);
        wsf[WS_TOPKP + tok * 2] = inv;
        wsf[WS_TOPKP + tok * 2 + 1] = ex * inv;
        e0a[j] = i0; e1a[j] = i1;
        atomicAdd(&cnt[i0], 1);
        atomicAdd(&cnt[i1], 1);
    }
    __syncthreads();
    if (t == 0) {
        int acc = 0;
        for (int e = 0; e < 8; e++) { base[e] = acc; acc += (cnt[e] + 127) & ~127; }
        base[8] = acc;
        for (int e = 0; e < 9; e++) wsi[WS_OFF + e] = base[e];
    }
    __syncthreads();
    for (int tt = t; tt < MAXT; tt += 256) {
        int rb = tt * 128, ex = 0;
        for (int e = 0; e < 8; e++)
            if (rb >= base[e] && rb < base[e + 1]) ex = e;
        wsi[WS_TEXP + tt] = ex;
    }
    #pragma unroll
    for (int j = 0; j < 8; j++) {
        int tok = t * 8 + j;
        int ee[2] = {e0a[j], e1a[j]};
        #pragma unroll
        for (int k = 0; k < 2; k++) {
            int e = ee[k];
            int slot = atomicAdd(&fill[e], 1);
            int r = base[e] + slot;
            wsi[WS_ROWTOK + r] = tok;
            wsi[WS_TOKROW + tok * 2 + k] = r;
        }
    }
}

// ---------------- prep_w1: pack w1 only (LDS-staged transpose) ----------------
// pw1 layout: block b=((e*32+ct)*32)+k0i holds [kg:4][n:128][kk:8],
//   k = k0i*32+kg*8+kk, col = (sub&1 ? I : 0) + ct*64 + (sub>>1)*32 + (n&31), sub=n>>5
__global__ __launch_bounds__(256) void prep_w1_kernel(
    const float* __restrict__ w1, unsigned short* __restrict__ pw1) {
    __shared__ __align__(16) unsigned short L[32 * 512];
    const int t = threadIdx.x;
    int b = blockIdx.x;
    int cs = b & 7, k0i = (b >> 3) & 31, e = b >> 8;
    const float* src = w1 + (size_t)e * H * N2 + (size_t)(k0i * 32) * N2 + cs * 512;
    #pragma unroll
    for (int i = 0; i < 8; i++) {
        int c = t + i * 256;                 // 2048 chunks x 8 elem
        int row = c >> 6, col8 = (c & 63) * 8;
        const float* sp = src + (size_t)row * N2 + col8;
        f32x4 a = *(const f32x4*)sp;
        f32x4 bb = *(const f32x4*)(sp + 4);
        s16x8 s = {f2bf(a[0]), f2bf(a[1]), f2bf(a[2]), f2bf(a[3]),
                   f2bf(bb[0]), f2bf(bb[1]), f2bf(bb[2]), f2bf(bb[3])};
        *(s16x8*)&L[c * 8] = s;
    }
    __syncthreads();
    int gate = cs >> 2;                      // slabs 4..7 are the gate half
    int ctbase = (cs & 3) * 8;
    unsigned short* dstb = pw1 + (size_t)(e * 1024 + k0i) * 4096;
    #pragma unroll
    for (int i = 0; i < 8; i++) {
        int cidx = t + i * 256;
        int within = cidx & 31, nhalf = (cidx >> 5) & 1;
        int kg = (cidx >> 6) & 3, ctp = cidx >> 8;
        int x = ctp * 64 + nhalf * 32 + within;          // LDS col
        int n = gate * 32 + nhalf * 64 + within;         // packed n
        s16x8 s;
        #pragma unroll
        for (int kk = 0; kk < 8; kk++) s[kk] = (short)L[(kg * 8 + kk) * 512 + x];
        int ct = ctbase + ctp;
        *(s16x8*)(dstb + (size_t)ct * 32 * 4096 + (kg * 128 + n) * 8) = s;
    }
}

// ---------------- fc1 (128x128, BK=32) + SwiGLU; blocks >= FC1_BLKS pack w2 (overlapped) ----------------
// pw2 layout: block b=((e*8+ht)*64)+k0i holds [kg:4][n:128][kk:8], col=ht*128+n
__global__ __launch_bounds__(256, 2) void fc1_kernel(
    const unsigned short* __restrict__ hsb, const unsigned short* __restrict__ pw1,
    const int* __restrict__ wsi, const unsigned short* __restrict__ zrow,
    unsigned short* __restrict__ act,
    const float* __restrict__ w2, unsigned short* __restrict__ pw2) {
    __shared__ __align__(16) unsigned short SM[32 * 512];   // 32 KB (union: fc1 Al|Bl / w2 tile)
    const int t = threadIdx.x;

    if (blockIdx.x >= FC1_BLKS) {
        // ---- w2 pack path (consumed only by fc2, which launches after us) ----
        int b = (int)blockIdx.x - FC1_BLKS;
        int cs = b & 1, k0i = (b >> 1) & 63, e = b >> 7;
        const float* src = w2 + (size_t)e * I * H + (size_t)(k0i * 32) * H + cs * 512;
        #pragma unroll
        for (int i = 0; i < 8; i++) {
            int c = t + i * 256;
            int row = c >> 6, col8 = (c & 63) * 8;
            const float* sp = src + (size_t)row * H + col8;
            f32x4 a = *(const f32x4*)sp;
            f32x4 bb = *(const f32x4*)(sp + 4);
            s16x8 s = {f2bf(a[0]), f2bf(a[1]), f2bf(a[2]), f2bf(a[3]),
                       f2bf(bb[0]), f2bf(bb[1]), f2bf(bb[2]), f2bf(bb[3])};
            *(s16x8*)&SM[c * 8] = s;
        }
        __syncthreads();
        unsigned short* dstb = pw2 + (size_t)(e * 512 + k0i) * 4096;
        #pragma unroll
        for (int i = 0; i < 8; i++) {
            int cidx = t + i * 256;
            int n = cidx & 127, kg = (cidx >> 7) & 3, htp = cidx >> 9;
            int x = htp * 128 + n;
            s16x8 s;
            #pragma unroll
            for (int kk = 0; kk < 8; kk++) s[kk] = (short)SM[(kg * 8 + kk) * 512 + x];
            int ht = cs * 4 + htp;
            *(s16x8*)(dstb + (size_t)ht * 64 * 4096 + (kg * 128 + n) * 8) = s;
        }
        return;
    }

    // ---- fc1 path ----
    unsigned short* Al = SM;                                // [kg:4][m:128][8]
    unsigned short* Bl = SM + 4096;                         // [kg:4][n:128][8]
    const int ct = blockIdx.x & 31, rt = blockIdx.x >> 5;
    const int rowb = rt * 128;
    if (rowb >= wsi[WS_OFF + 8]) return;
    const int e = wsi[WS_TEXP + rt];
    const unsigned short* pb = pw1 + (size_t)((e * 32 + ct) * 32) * 4096;

    const int m = t & 127;
    const int tok = wsi[WS_ROWTOK + rowb + m];
    const unsigned short* rp = (tok >= 0) ? (hsb + (size_t)tok * H) : zrow;
    const int kga = t >> 7;

    const int lane = t & 63, w = t >> 6, wr = w >> 1, wc = w & 1;
    const int q = lane >> 4, l16 = lane & 15;

    f32x4 zero = {0.f, 0.f, 0.f, 0.f};
    f32x4 acc[4][4];
    #pragma unroll
    for (int mi = 0; mi < 4; mi++)
        #pragma unroll
        for (int ni = 0; ni < 4; ni++) acc[mi][ni] = zero;

    for (int k0i = 0; k0i < 32; k0i++) {
        const int k0 = k0i * 32;
        gl2lds16(rp + k0 + kga * 8, &Al[t * 8]);
        gl2lds16(rp + k0 + (kga + 2) * 8, &Al[(t + 256) * 8]);
        const unsigned short* ps = pb + (size_t)k0i * 4096;
        gl2lds16(ps + t * 8, &Bl[t * 8]);
        gl2lds16(ps + (t + 256) * 8, &Bl[(t + 256) * 8]);
        __syncthreads();

        s16x8 af[4], bf[4];
        #pragma unroll
        for (int mi = 0; mi < 4; mi++)
            af[mi] = *(const s16x8*)&Al[(q * 128 + wr * 64 + mi * 16 + l16) * 8];
        #pragma unroll
        for (int ni = 0; ni < 4; ni++)
            bf[ni] = *(const s16x8*)&Bl[(q * 128 + wc * 64 + ni * 16 + l16) * 8];
        #pragma unroll
        for (int mi = 0; mi < 4; mi++)
            #pragma unroll
            for (int ni = 0; ni < 4; ni++)
                acc[mi][ni] = MFMA16(af[mi], bf[ni], acc[mi][ni]);
        __syncthreads();
    }

    // epilogue: wave cols = 32 proj + 32 gate (ni 0,1 = proj; ni 2,3 = matching gate)
    #pragma unroll
    for (int mi = 0; mi < 4; mi++)
        #pragma unroll
        for (int r = 0; r < 4; r++) {
            int row = rowb + wr * 64 + mi * 16 + q * 4 + r;
            #pragma unroll
            for (int ni = 0; ni < 2; ni++) {
                int col = ct * 64 + wc * 32 + ni * 16 + l16;
                float p = acc[mi][ni][r], g = acc[mi][ni + 2][r];
                float val = p * g / (1.f + __expf(-p));
                act[(size_t)row * I + col] = (unsigned short)f2bf(val);
            }
        }
}

// ---------------- fc2 (128x128, BK=32, K-split x2) -> eo partials, no atomics ----------------
__global__ __launch_bounds__(256, 2) void fc2_kernel(
    const unsigned short* __restrict__ act, const unsigned short* __restrict__ pw2,
    const int* __restrict__ wsi, float* __restrict__ eo) {
    __shared__ __align__(16) unsigned short Al[512 * 8];
    __shared__ __align__(16) unsigned short Bl[512 * 8];
    const int t = threadIdx.x;
    const int ht = blockIdx.x, rt = blockIdx.y, ks = blockIdx.z;
    const int rowb = rt * 128;
    if (rowb >= wsi[WS_OFF + 8]) return;
    const int e = wsi[WS_TEXP + rt];
    const unsigned short* pb = pw2 + (size_t)((e * 8 + ht) * 64) * 4096;

    const int m = t & 127;
    const unsigned short* rp = act + (size_t)(rowb + m) * I;
    const int kga = t >> 7;

    const int lane = t & 63, w = t >> 6, wr = w >> 1, wc = w & 1;
    const int q = lane >> 4, l16 = lane & 15;

    f32x4 zero = {0.f, 0.f, 0.f, 0.f};
    f32x4 acc[4][4];
    #pragma unroll
    for (int mi = 0; mi < 4; mi++)
        #pragma unroll
        for (int ni = 0; ni < 4; ni++) acc[mi][ni] = zero;

    for (int k0i = ks * 32; k0i < ks * 32 + 32; k0i++) {
        const int k0 = k0i * 32;
        gl2lds16(rp + k0 + kga * 8, &Al[t * 8]);
        gl2lds16(rp + k0 + (kga + 2) * 8, &Al[(t + 256) * 8]);
        const unsigned short* ps = pb + (size_t)k0i * 4096;
        gl2lds16(ps + t * 8, &Bl[t * 8]);
        gl2lds16(ps + (t + 256) * 8, &Bl[(t + 256) * 8]);
        __syncthreads();

        s16x8 af[4], bf[4];
        #pragma unroll
        for (int mi = 0; mi < 4; mi++)
            af[mi] = *(const s16x8*)&Al[(q * 128 + wr * 64 + mi * 16 + l16) * 8];
        #pragma unroll
        for (int ni = 0; ni < 4; ni++)
            bf[ni] = *(const s16x8*)&Bl[(q * 128 + wc * 64 + ni * 16 + l16) * 8];
        #pragma unroll
        for (int mi = 0; mi < 4; mi++)
            #pragma unroll
            for (int ni = 0; ni < 4; ni++)
                acc[mi][ni] = MFMA16(af[mi], bf[ni], acc[mi][ni]);
        __syncthreads();
    }

    float* ed = eo + (size_t)ks * RCAP * H;
    #pragma unroll
    for (int mi = 0; mi < 4; mi++)
        #pragma unroll
        for (int r = 0; r < 4; r++) {
            int row = rowb + wr * 64 + mi * 16 + q * 4 + r;
            #pragma unroll
            for (int ni = 0; ni < 4; ni++) {
                int col = ht * 128 + wc * 64 + ni * 16 + l16;
                ed[(size_t)row * H + col] = acc[mi][ni][r];
            }
        }
}

// ---------------- combine: out[tok] = s0*(eo0[r0]+eo1[r0]) + s1*(eo0[r1]+eo1[r1]) ----------------
__global__ __launch_bounds__(256) void combine_kernel(
    const float* __restrict__ eo, const int* __restrict__ wsi,
    const float* __restrict__ wsf, float* __restrict__ out) {
    const int tok = blockIdx.x;
    const int r0 = wsi[WS_TOKROW + tok * 2], r1 = wsi[WS_TOKROW + tok * 2 + 1];
    const float s0 = wsf[WS_TOPKP + tok * 2], s1 = wsf[WS_TOPKP + tok * 2 + 1];
    const float* a0 = eo + (size_t)r0 * H;
    const float* a1 = eo + (size_t)RCAP * H + (size_t)r0 * H;
    const float* b0 = eo + (size_t)r1 * H;
    const float* b1 = eo + (size_t)RCAP * H + (size_t)r1 * H;
    const int c = threadIdx.x * 4;
    f32x4 va0 = *(const f32x4*)(a0 + c), va1 = *(const f32x4*)(a1 + c);
    f32x4 vb0 = *(const f32x4*)(b0 + c), vb1 = *(const f32x4*)(b1 + c);
    f32x4 r;
    #pragma unroll
    for (int i = 0; i < 4; i++) r[i] = s0 * (va0[i] + va1[i]) + s1 * (vb0[i] + vb1[i]);
    *(f32x4*)(out + (size_t)tok * H + c) = r;
}

extern "C" void kernel_launch(void* const* d_in, const int* in_sizes, int n_in,
                              void* d_out, int out_size, void* d_ws, size_t ws_size,
                              hipStream_t stream) {
    const float* hs     = (const float*)d_in[0];
    const float* logits = (const float*)d_in[1];
    const float* w1     = (const float*)d_in[2];
    const float* w2     = (const float*)d_in[3];
    float* out = (float*)d_out;
    int* wsi = (int*)d_ws;
    float* wsf = (float*)d_ws;
    unsigned short* zrow = (unsigned short*)((char*)d_ws + WSB_ZROW);
    unsigned short* hsb  = (unsigned short*)((char*)d_ws + WSB_HSB);
    unsigned short* act  = (unsigned short*)((char*)d_ws + WSB_ACT);
    unsigned short* pw1  = (unsigned short*)((char*)d_ws + WSB_PW1);
    unsigned short* pw2  = (unsigned short*)((char*)d_ws + WSB_PW2);
    float* eo = (float*)((char*)d_ws + WSB_PW1);   // aliases pw1 (consumed by fc1 before fc2 runs)

    routing_hs_kernel<<<1 + HSB_BLKS, 256, 0, stream>>>(logits, wsi, wsf, hs, hsb);
    prep_w1_kernel<<<W1T_BLKS, 256, 0, stream>>>(w1, pw1);
    fc1_kernel<<<FC1_BLKS + W2T_BLKS, 256, 0, stream>>>(hsb, pw1, wsi, zrow, act, w2, pw2);
    fc2_kernel<<<dim3(8, MAXT, 2), 256, 0, stream>>>(act, pw2, wsi, eo);
    combine_kernel<<<T, 256, 0, stream>>>(eo, wsi, wsf, out);
}

// Round 3
// 367.258 us; speedup vs baseline: 1.0424x; 1.0131x over previous
//
#include <hip/hip_runtime.h>
#include <hip/hip_bf16.h>

// Problem constants (AriaExperts): tokens=2048, hidden=1024, inter=2048, E=8, topk=2
constexpr int T = 2048;
constexpr int H = 1024;
constexpr int I = 2048;
constexpr int N2 = 2 * I;      // fc1 weight cols (proj|gate)
constexpr int RCAP = 5120;     // padded row capacity
constexpr int MAXT = 40;       // max 128-row tiles

// ws int-offset map (ints)
constexpr int WS_OFF = 16;                 // [16,25) expert row offsets (padded)
constexpr int WS_TEXP = 32;                // [32,72) tile -> expert
constexpr int WS_TOPKP = 4256;             // [4256,8352) token scales (float)
constexpr int WS_ROWTOK = 8352;            // [8352,13472) row -> token
constexpr int WS_TOKROW = 13472;           // [13472,17568) token -> 2 rows
// ws byte offsets
constexpr size_t WSB_ZROW = 114688;        // bf16 zero row, H elements
constexpr size_t WSB_HSB  = 131072;        // bf16 hidden_states [T][H] (4 MB)
constexpr size_t WSB_ACT  = 8u << 20;      // bf16 act [RCAP][I] (20 MB)
constexpr size_t WSB_PW1  = 32u << 20;     // packed bf16 w1 (64 MB); reused as eo[2][RCAP][H] fp32 (40 MB)
constexpr size_t WSB_PW2  = 96u << 20;     // packed bf16 w2 (32 MB) -> 128 MB ws

// grids
constexpr int W1T_BLKS = 8 * 32 * 8;       // e * k0i * colslab(512)  = 2048
constexpr int W2T_BLKS = 8 * 64 * 2;       // e * k0i * colslab(512)  = 1024
constexpr int HSB_BLKS = T * H / 2048;     // 1024
constexpr int FC1_BLKS = 32 * MAXT;        // 1280

typedef __attribute__((ext_vector_type(4))) float f32x4;
typedef __attribute__((ext_vector_type(8))) short s16x8;

__device__ __forceinline__ short f2bf(float f) {
    unsigned u = __float_as_uint(f);
    u += 0x7FFFu + ((u >> 16) & 1u);   // round-to-nearest-even
    return (short)(u >> 16);
}

#define MFMA16(a, b, c) __builtin_amdgcn_mfma_f32_16x16x32_bf16(a, b, c, 0, 0, 0)

__device__ __forceinline__ void gl2lds16(const void* g, void* l) {
    __builtin_amdgcn_global_load_lds(
        (const __attribute__((address_space(1))) void*)g,
        (__attribute__((address_space(3))) void*)l, 16, 0, 0);
}

// ---------------- pre: w1-pack (blocks [0,W1T)), routing (block W1T), hs->bf16 (rest) ----------------
// pw1 layout: block b=((e*32+ct)*32)+k0i holds [kg:4][n:128][kk:8],
//   k = k0i*32+kg*8+kk, col = (sub&1 ? I : 0) + ct*64 + (sub>>1)*32 + (n&31), sub=n>>5
__global__ __launch_bounds__(256) void pre_kernel(const float* __restrict__ logits,
                                                  int* __restrict__ wsi,
                                                  float* __restrict__ wsf,
                                                  const float* __restrict__ hs,
                                                  unsigned short* __restrict__ hsb,
                                                  const float* __restrict__ w1,
                                                  unsigned short* __restrict__ pw1) {
    __shared__ __align__(16) unsigned short L[32 * 512];   // 32 KB (w1 tile / routing scratch)
    const int t = threadIdx.x;

    if (blockIdx.x < W1T_BLKS) {
        // ---- w1 pack (LDS-staged transpose) ----
        int b = blockIdx.x;
        int cs = b & 7, k0i = (b >> 3) & 31, e = b >> 8;
        const float* src = w1 + (size_t)e * H * N2 + (size_t)(k0i * 32) * N2 + cs * 512;
        #pragma unroll
        for (int i = 0; i < 8; i++) {
            int c = t + i * 256;                 // 2048 chunks x 8 elem
            int row = c >> 6, col8 = (c & 63) * 8;
            const float* sp = src + (size_t)row * N2 + col8;
            f32x4 a = *(const f32x4*)sp;
            f32x4 bb = *(const f32x4*)(sp + 4);
            s16x8 s = {f2bf(a[0]), f2bf(a[1]), f2bf(a[2]), f2bf(a[3]),
                       f2bf(bb[0]), f2bf(bb[1]), f2bf(bb[2]), f2bf(bb[3])};
            *(s16x8*)&L[c * 8] = s;
        }
        __syncthreads();
        int gate = cs >> 2;                      // slabs 4..7 are the gate half
        int ctbase = (cs & 3) * 8;
        unsigned short* dstb = pw1 + (size_t)(e * 1024 + k0i) * 4096;
        #pragma unroll
        for (int i = 0; i < 8; i++) {
            int cidx = t + i * 256;
            int within = cidx & 31, nhalf = (cidx >> 5) & 1;
            int kg = (cidx >> 6) & 3, ctp = cidx >> 8;
            int x = ctp * 64 + nhalf * 32 + within;          // LDS col
            int n = gate * 32 + nhalf * 64 + within;         // packed n
            s16x8 s;
            #pragma unroll
            for (int kk = 0; kk < 8; kk++) s[kk] = (short)L[(kg * 8 + kk) * 512 + x];
            int ct = ctbase + ctp;
            *(s16x8*)(dstb + (size_t)ct * 32 * 4096 + (kg * 128 + n) * 8) = s;
        }
        return;
    }
    if (blockIdx.x > W1T_BLKS) {
        // ---- hs -> bf16, streaming ----
        int i = (((int)blockIdx.x - W1T_BLKS - 1) * 256 + t) * 8;
        f32x4 a = *(const f32x4*)(hs + i);
        f32x4 b = *(const f32x4*)(hs + i + 4);
        s16x8 s = {f2bf(a[0]), f2bf(a[1]), f2bf(a[2]), f2bf(a[3]),
                   f2bf(b[0]), f2bf(b[1]), f2bf(b[2]), f2bf(b[3])};
        *(s16x8*)(hsb + i) = s;
        return;
    }

    // ---- routing (single block) ----
    int* cnt  = (int*)L;
    int* base = cnt + 8;
    int* fill = base + 9;
    if (t < 8) { cnt[t] = 0; fill[t] = 0; }
    for (int r = t; r < RCAP; r += 256) wsi[WS_ROWTOK + r] = -1;
    unsigned short* zr = (unsigned short*)((char*)wsi + WSB_ZROW);
    for (int i = t; i < H; i += 256) zr[i] = 0;
    __syncthreads();

    int e0a[8], e1a[8];
    #pragma unroll
    for (int j = 0; j < 8; j++) {
        int tok = t * 8 + j;
        const float* l = logits + tok * 8;
        float v0 = -1e30f; int i0 = 0;
        #pragma unroll
        for (int i = 0; i < 8; i++) { float v = l[i]; if (v > v0) { v0 = v; i0 = i; } }
        float v1 = -1e30f; int i1 = 0;
        #pragma unroll
        for (int i = 0; i < 8; i++) { if (i == i0) continue; float v = l[i]; if (v > v1) { v1 = v; i1 = i; } }
        float ex = __expf(v1 - v0);
        float inv = 1.f / (1.f + ex);
        wsf[WS_TOPKP + tok * 2] = inv;
        wsf[WS_TOPKP + tok * 2 + 1] = ex * inv;
        e0a[j] = i0; e1a[j] = i1;
        atomicAdd(&cnt[i0], 1);
        atomicAdd(&cnt[i1], 1);
    }
    __syncthreads();
    if (t == 0) {
        int acc = 0;
        for (int e = 0; e < 8; e++) { base[e] = acc; acc += (cnt[e] + 127) & ~127; }
        base[8] = acc;
        for (int e = 0; e < 9; e++) wsi[WS_OFF + e] = base[e];
    }
    __syncthreads();
    for (int tt = t; tt < MAXT; tt += 256) {
        int rb = tt * 128, ex = 0;
        for (int e = 0; e < 8; e++)
            if (rb >= base[e] && rb < base[e + 1]) ex = e;
        wsi[WS_TEXP + tt] = ex;
    }
    #pragma unroll
    for (int j = 0; j < 8; j++) {
        int tok = t * 8 + j;
        int ee[2] = {e0a[j], e1a[j]};
        #pragma unroll
        for (int k = 0; k < 2; k++) {
            int e = ee[k];
            int slot = atomicAdd(&fill[e], 1);
            int r = base[e] + slot;
            wsi[WS_ROWTOK + r] = tok;
            wsi[WS_TOKROW + tok * 2 + k] = r;
        }
    }
}

// ---------------- fc1 (128x128, BK=32, double-buffered prefetch) + SwiGLU ----------------
// blocks >= FC1_BLKS pack w2 (overlapped; consumed only by fc2)
// pw2 layout: block b=((e*8+ht)*64)+k0i holds [kg:4][n:128][kk:8], col=ht*128+n
__global__ __launch_bounds__(256, 4) void fc1_kernel(
    const unsigned short* __restrict__ hsb, const unsigned short* __restrict__ pw1,
    const int* __restrict__ wsi, const unsigned short* __restrict__ zrow,
    unsigned short* __restrict__ act,
    const float* __restrict__ w2, unsigned short* __restrict__ pw2) {
    __shared__ __align__(16) unsigned short SM[32 * 512];   // 32 KB: A0|B0|A1|B1 (or w2 tile)
    const int t = threadIdx.x;

    if (blockIdx.x >= FC1_BLKS) {
        // ---- w2 pack path ----
        int b = (int)blockIdx.x - FC1_BLKS;
        int cs = b & 1, k0i = (b >> 1) & 63, e = b >> 7;
        const float* src = w2 + (size_t)e * I * H + (size_t)(k0i * 32) * H + cs * 512;
        #pragma unroll
        for (int i = 0; i < 8; i++) {
            int c = t + i * 256;
            int row = c >> 6, col8 = (c & 63) * 8;
            const float* sp = src + (size_t)row * H + col8;
            f32x4 a = *(const f32x4*)sp;
            f32x4 bb = *(const f32x4*)(sp + 4);
            s16x8 s = {f2bf(a[0]), f2bf(a[1]), f2bf(a[2]), f2bf(a[3]),
                       f2bf(bb[0]), f2bf(bb[1]), f2bf(bb[2]), f2bf(bb[3])};
            *(s16x8*)&SM[c * 8] = s;
        }
        __syncthreads();
        unsigned short* dstb = pw2 + (size_t)(e * 512 + k0i) * 4096;
        #pragma unroll
        for (int i = 0; i < 8; i++) {
            int cidx = t + i * 256;
            int n = cidx & 127, kg = (cidx >> 7) & 3, htp = cidx >> 9;
            int x = htp * 128 + n;
            s16x8 s;
            #pragma unroll
            for (int kk = 0; kk < 8; kk++) s[kk] = (short)SM[(kg * 8 + kk) * 512 + x];
            int ht = cs * 4 + htp;
            *(s16x8*)(dstb + (size_t)ht * 64 * 4096 + (kg * 128 + n) * 8) = s;
        }
        return;
    }

    // ---- fc1 path ----
    unsigned short* A0 = SM;            // [kg:4][m:128][8]
    unsigned short* B0 = SM + 4096;     // [kg:4][n:128][8]
    unsigned short* A1 = SM + 8192;
    unsigned short* B1 = SM + 12288;
    const int ct = blockIdx.x & 31, rt = blockIdx.x >> 5;
    const int rowb = rt * 128;
    if (rowb >= wsi[WS_OFF + 8]) return;
    const int e = wsi[WS_TEXP + rt];
    const unsigned short* pb = pw1 + (size_t)((e * 32 + ct) * 32) * 4096;

    const int m = t & 127;
    const int tok = wsi[WS_ROWTOK + rowb + m];
    const unsigned short* rp = (tok >= 0) ? (hsb + (size_t)tok * H) : zrow;
    const int kga = t >> 7;

    const int lane = t & 63, w = t >> 6, wr = w >> 1, wc = w & 1;
    const int q = lane >> 4, l16 = lane & 15;

    f32x4 zero = {0.f, 0.f, 0.f, 0.f};
    f32x4 acc[4][4];
    #pragma unroll
    for (int mi = 0; mi < 4; mi++)
        #pragma unroll
        for (int ni = 0; ni < 4; ni++) acc[mi][ni] = zero;

    #define FC1_STAGE(k0i, Ab, Bb)                                             \
        do {                                                                   \
            const int k0_ = (k0i) * 32;                                        \
            gl2lds16(rp + k0_ + kga * 8, &(Ab)[t * 8]);                        \
            gl2lds16(rp + k0_ + (kga + 2) * 8, &(Ab)[(t + 256) * 8]);          \
            const unsigned short* ps_ = pb + (size_t)(k0i) * 4096;             \
            gl2lds16(ps_ + t * 8, &(Bb)[t * 8]);                               \
            gl2lds16(ps_ + (t + 256) * 8, &(Bb)[(t + 256) * 8]);               \
        } while (0)

    #define FC1_COMPUTE(Ab, Bb)                                                \
        do {                                                                   \
            s16x8 af[4], bf[4];                                                \
            _Pragma("unroll")                                                  \
            for (int mi = 0; mi < 4; mi++)                                     \
                af[mi] = *(const s16x8*)&(Ab)[(q * 128 + wr * 64 + mi * 16 + l16) * 8]; \
            _Pragma("unroll")                                                  \
            for (int ni = 0; ni < 4; ni++)                                     \
                bf[ni] = *(const s16x8*)&(Bb)[(q * 128 + wc * 64 + ni * 16 + l16) * 8]; \
            _Pragma("unroll")                                                  \
            for (int mi = 0; mi < 4; mi++)                                     \
                _Pragma("unroll")                                              \
                for (int ni = 0; ni < 4; ni++)                                 \
                    acc[mi][ni] = MFMA16(af[mi], bf[ni], acc[mi][ni]);         \
        } while (0)

    FC1_STAGE(0, A0, B0);
    __syncthreads();
    for (int k0i = 0; k0i < 32; k0i += 2) {
        FC1_STAGE(k0i + 1, A1, B1);        // issue next-tile loads BEFORE compute
        FC1_COMPUTE(A0, B0);
        __syncthreads();                   // drains vmcnt (next tile ready) + barrier
        if (k0i + 2 < 32) FC1_STAGE(k0i + 2, A0, B0);
        FC1_COMPUTE(A1, B1);
        __syncthreads();
    }

    // epilogue: wave cols = 32 proj + 32 gate (ni 0,1 = proj; ni 2,3 = matching gate)
    #pragma unroll
    for (int mi = 0; mi < 4; mi++)
        #pragma unroll
        for (int r = 0; r < 4; r++) {
            int row = rowb + wr * 64 + mi * 16 + q * 4 + r;
            #pragma unroll
            for (int ni = 0; ni < 2; ni++) {
                int col = ct * 64 + wc * 32 + ni * 16 + l16;
                float p = acc[mi][ni][r], g = acc[mi][ni + 2][r];
                float val = p * g / (1.f + __expf(-p));
                act[(size_t)row * I + col] = (unsigned short)f2bf(val);
            }
        }
}

// ---------------- fc2 (128x128, BK=32, K-split x2, double-buffered prefetch) -> eo partials ----------------
__global__ __launch_bounds__(256, 4) void fc2_kernel(
    const unsigned short* __restrict__ act, const unsigned short* __restrict__ pw2,
    const int* __restrict__ wsi, float* __restrict__ eo) {
    __shared__ __align__(16) unsigned short SM[32 * 512];   // A0|B0|A1|B1
    unsigned short* A0 = SM;
    unsigned short* B0 = SM + 4096;
    unsigned short* A1 = SM + 8192;
    unsigned short* B1 = SM + 12288;
    const int t = threadIdx.x;
    const int ht = blockIdx.x, rt = blockIdx.y, ks = blockIdx.z;
    const int rowb = rt * 128;
    if (rowb >= wsi[WS_OFF + 8]) return;
    const int e = wsi[WS_TEXP + rt];
    const unsigned short* pb = pw2 + (size_t)((e * 8 + ht) * 64) * 4096;

    const int m = t & 127;
    const unsigned short* rp = act + (size_t)(rowb + m) * I;
    const int kga = t >> 7;

    const int lane = t & 63, w = t >> 6, wr = w >> 1, wc = w & 1;
    const int q = lane >> 4, l16 = lane & 15;

    f32x4 zero = {0.f, 0.f, 0.f, 0.f};
    f32x4 acc[4][4];
    #pragma unroll
    for (int mi = 0; mi < 4; mi++)
        #pragma unroll
        for (int ni = 0; ni < 4; ni++) acc[mi][ni] = zero;

    #define FC2_STAGE(k0i, Ab, Bb)                                             \
        do {                                                                   \
            const int k0_ = (k0i) * 32;                                        \
            gl2lds16(rp + k0_ + kga * 8, &(Ab)[t * 8]);                        \
            gl2lds16(rp + k0_ + (kga + 2) * 8, &(Ab)[(t + 256) * 8]);          \
            const unsigned short* ps_ = pb + (size_t)(k0i) * 4096;             \
            gl2lds16(ps_ + t * 8, &(Bb)[t * 8]);                               \
            gl2lds16(ps_ + (t + 256) * 8, &(Bb)[(t + 256) * 8]);               \
        } while (0)

    #define FC2_COMPUTE(Ab, Bb)                                                \
        do {                                                                   \
            s16x8 af[4], bf[4];                                                \
            _Pragma("unroll")                                                  \
            for (int mi = 0; mi < 4; mi++)                                     \
                af[mi] = *(const s16x8*)&(Ab)[(q * 128 + wr * 64 + mi * 16 + l16) * 8]; \
            _Pragma("unroll")                                                  \
            for (int ni = 0; ni < 4; ni++)                                     \
                bf[ni] = *(const s16x8*)&(Bb)[(q * 128 + wc * 64 + ni * 16 + l16) * 8]; \
            _Pragma("unroll")                                                  \
            for (int mi = 0; mi < 4; mi++)                                     \
                _Pragma("unroll")                                              \
                for (int ni = 0; ni < 4; ni++)                                 \
                    acc[mi][ni] = MFMA16(af[mi], bf[ni], acc[mi][ni]);         \
        } while (0)

    const int kb = ks * 32;
    FC2_STAGE(kb, A0, B0);
    __syncthreads();
    for (int j = 0; j < 32; j += 2) {
        FC2_STAGE(kb + j + 1, A1, B1);
        FC2_COMPUTE(A0, B0);
        __syncthreads();
        if (j + 2 < 32) FC2_STAGE(kb + j + 2, A0, B0);
        FC2_COMPUTE(A1, B1);
        __syncthreads();
    }

    float* ed = eo + (size_t)ks * RCAP * H;
    #pragma unroll
    for (int mi = 0; mi < 4; mi++)
        #pragma unroll
        for (int r = 0; r < 4; r++) {
            int row = rowb + wr * 64 + mi * 16 + q * 4 + r;
            #pragma unroll
            for (int ni = 0; ni < 4; ni++) {
                int col = ht * 128 + wc * 64 + ni * 16 + l16;
                ed[(size_t)row * H + col] = acc[mi][ni][r];
            }
        }
}

// ---------------- combine: out[tok] = s0*(eo0[r0]+eo1[r0]) + s1*(eo0[r1]+eo1[r1]) ----------------
__global__ __launch_bounds__(256) void combine_kernel(
    const float* __restrict__ eo, const int* __restrict__ wsi,
    const float* __restrict__ wsf, float* __restrict__ out) {
    const int tok = blockIdx.x;
    const int r0 = wsi[WS_TOKROW + tok * 2], r1 = wsi[WS_TOKROW + tok * 2 + 1];
    const float s0 = wsf[WS_TOPKP + tok * 2], s1 = wsf[WS_TOPKP + tok * 2 + 1];
    const float* a0 = eo + (size_t)r0 * H;
    const float* a1 = eo + (size_t)RCAP * H + (size_t)r0 * H;
    const float* b0 = eo + (size_t)r1 * H;
    const float* b1 = eo + (size_t)RCAP * H + (size_t)r1 * H;
    const int c = threadIdx.x * 4;
    f32x4 va0 = *(const f32x4*)(a0 + c), va1 = *(const f32x4*)(a1 + c);
    f32x4 vb0 = *(const f32x4*)(b0 + c), vb1 = *(const f32x4*)(b1 + c);
    f32x4 r;
    #pragma unroll
    for (int i = 0; i < 4; i++) r[i] = s0 * (va0[i] + va1[i]) + s1 * (vb0[i] + vb1[i]);
    *(f32x4*)(out + (size_t)tok * H + c) = r;
}

extern "C" void kernel_launch(void* const* d_in, const int* in_sizes, int n_in,
                              void* d_out, int out_size, void* d_ws, size_t ws_size,
                              hipStream_t stream) {
    const float* hs     = (const float*)d_in[0];
    const float* logits = (const float*)d_in[1];
    const float* w1     = (const float*)d_in[2];
    const float* w2     = (const float*)d_in[3];
    float* out = (float*)d_out;
    int* wsi = (int*)d_ws;
    float* wsf = (float*)d_ws;
    unsigned short* zrow = (unsigned short*)((char*)d_ws + WSB_ZROW);
    unsigned short* hsb  = (unsigned short*)((char*)d_ws + WSB_HSB);
    unsigned short* act  = (unsigned short*)((char*)d_ws + WSB_ACT);
    unsigned short* pw1  = (unsigned short*)((char*)d_ws + WSB_PW1);
    unsigned short* pw2  = (unsigned short*)((char*)d_ws + WSB_PW2);
    float* eo = (float*)((char*)d_ws + WSB_PW1);   // aliases pw1 (consumed by fc1 before fc2 runs)

    pre_kernel<<<W1T_BLKS + 1 + HSB_BLKS, 256, 0, stream>>>(logits, wsi, wsf, hs, hsb, w1, pw1);
    fc1_kernel<<<FC1_BLKS + W2T_BLKS, 256, 0, stream>>>(hsb, pw1, wsi, zrow, act, w2, pw2);
    fc2_kernel<<<dim3(8, MAXT, 2), 256, 0, stream>>>(act, pw2, wsi, eo);
    combine_kernel<<<T, 256, 0, stream>>>(eo, wsi, wsf, out);
}

// Round 4
// 353.835 us; speedup vs baseline: 1.0819x; 1.0379x over previous
//
#include <hip/hip_runtime.h>
#include <hip/hip_bf16.h>

// Problem constants (AriaExperts): tokens=2048, hidden=1024, inter=2048, E=8, topk=2
constexpr int T = 2048;
constexpr int H = 1024;
constexpr int I = 2048;
constexpr int N2 = 2 * I;      // fc1 weight cols (proj|gate)
constexpr int RCAP = 5120;     // padded row capacity
constexpr int MAXT = 40;       // max 128-row tiles

// ws int-offset map (ints)
constexpr int WS_OFF = 16;                 // [16,25) expert row offsets (padded)
constexpr int WS_TEXP = 32;                // [32,72) tile -> expert
constexpr int WS_TOPKP = 4256;             // [4256,8352) token scales (float)
constexpr int WS_ROWTOK = 8352;            // [8352,13472) row -> token
constexpr int WS_TOKROW = 13472;           // [13472,17568) token -> 2 rows
// ws byte offsets
constexpr size_t WSB_ZROW = 114688;        // bf16 zero row, H elements
constexpr size_t WSB_HSB  = 131072;        // bf16 hidden_states [T][H] (4 MB)
constexpr size_t WSB_ACT  = 8u << 20;      // bf16 act [RCAP][I] (20 MB)
constexpr size_t WSB_PW1  = 32u << 20;     // packed bf16 w1 (64 MB); reused as eo[2][RCAP][H] fp32 (40 MB)
constexpr size_t WSB_PW2  = 96u << 20;     // packed bf16 w2 (32 MB) -> 128 MB ws

// grids
constexpr int W1T_BLKS = 8 * 32 * 16;      // e * k0i * colslab(256)  = 4096
constexpr int W2T_BLKS = 8 * 64 * 4;       // e * k0i * colslab(256)  = 2048
constexpr int HSB_BLKS = T * H / 2048;     // 1024
constexpr int FC1_BLKS = 32 * MAXT;        // 1280

typedef __attribute__((ext_vector_type(4))) float f32x4;
typedef __attribute__((ext_vector_type(8))) short s16x8;

__device__ __forceinline__ short f2bf(float f) {
    unsigned u = __float_as_uint(f);
    u += 0x7FFFu + ((u >> 16) & 1u);   // round-to-nearest-even
    return (short)(u >> 16);
}

#define MFMA16(a, b, c) __builtin_amdgcn_mfma_f32_16x16x32_bf16(a, b, c, 0, 0, 0)

__device__ __forceinline__ void gl2lds16(const void* g, void* l) {
    __builtin_amdgcn_global_load_lds(
        (const __attribute__((address_space(1))) void*)g,
        (__attribute__((address_space(3))) void*)l, 16, 0, 0);
}

// counted-vmcnt sync primitives (T4): never drain vmcnt to 0 inside the K-loop
#define VM_WAIT4 asm volatile("s_waitcnt vmcnt(4)" ::: "memory")
#define VM_WAIT0 asm volatile("s_waitcnt vmcnt(0)" ::: "memory")
#define BARRIER                                     \
    do {                                            \
        asm volatile("" ::: "memory");              \
        __builtin_amdgcn_s_barrier();               \
        asm volatile("" ::: "memory");              \
    } while (0)

// ---------------- pre: w1-pack (blocks [0,W1T)), routing (block W1T), hs->bf16 (rest) ----------------
// w1-pack: phase 1 stages a [k:32][c:256] fp32 tile via global_load_lds (8 x 16B per thread,
// all in flight -> latency hidden by MLP); phase 2 gathers 8 k's per output chunk from LDS
// (stride 1KB = 2 lanes/bank, free), converts to bf16, writes 16B chunks (512B runs/wave).
// pw1 layout: block ((e*32+ct)*32)+k0i holds [kg:4][n:128][kk:8];
//   col = (sub&1 ? I : 0) + ct*64 + (sub>>1)*32 + (n&31), sub=n>>5
__global__ __launch_bounds__(256) void pre_kernel(const float* __restrict__ logits,
                                                  int* __restrict__ wsi,
                                                  float* __restrict__ wsf,
                                                  const float* __restrict__ hs,
                                                  unsigned short* __restrict__ hsb,
                                                  const float* __restrict__ w1,
                                                  unsigned short* __restrict__ pw1) {
    __shared__ __align__(16) float Lf[32 * 256];   // 32 KB
    const int t = threadIdx.x;

    if (blockIdx.x < W1T_BLKS) {
        int b = blockIdx.x;
        int cs = b & 15, k0i = (b >> 4) & 31, e = b >> 9;
        const float* src = w1 + (size_t)e * H * N2 + (size_t)(k0i * 32) * N2 + cs * 256;
        #pragma unroll
        for (int i = 0; i < 8; i++) {
            int c = t + i * 256;                 // 2048 x 16B chunks
            int row = c >> 6, col4 = (c & 63) * 4;
            gl2lds16(src + (size_t)row * N2 + col4, &Lf[c * 4]);
        }
        __syncthreads();
        int gatebit = cs >> 3, csl = cs & 7;
        #pragma unroll
        for (int i = 0; i < 4; i++) {
            int cidx = t + i * 256;              // 1024 output chunks
            int within = cidx & 31, subh = (cidx >> 5) & 1;
            int kg = (cidx >> 6) & 3, ctp = cidx >> 8;
            int x = ctp * 64 + subh * 32 + within;           // LDS col
            s16x8 s;
            #pragma unroll
            for (int kk = 0; kk < 8; kk++) s[kk] = f2bf(Lf[(kg * 8 + kk) * 256 + x]);
            int n = gatebit * 32 + subh * 64 + within;       // packed n
            int ct = csl * 4 + ctp;
            *(s16x8*)(pw1 + ((size_t)(e * 32 + ct) * 32 + k0i) * 4096 + (kg * 128 + n) * 8) = s;
        }
        return;
    }
    if (blockIdx.x > W1T_BLKS) {
        // ---- hs -> bf16, streaming ----
        int i = (((int)blockIdx.x - W1T_BLKS - 1) * 256 + t) * 8;
        f32x4 a = *(const f32x4*)(hs + i);
        f32x4 b = *(const f32x4*)(hs + i + 4);
        s16x8 s = {f2bf(a[0]), f2bf(a[1]), f2bf(a[2]), f2bf(a[3]),
                   f2bf(b[0]), f2bf(b[1]), f2bf(b[2]), f2bf(b[3])};
        *(s16x8*)(hsb + i) = s;
        return;
    }

    // ---- routing (single block) ----
    int* cnt  = (int*)Lf;
    int* base = cnt + 8;
    int* fill = base + 9;
    if (t < 8) { cnt[t] = 0; fill[t] = 0; }
    for (int r = t; r < RCAP; r += 256) wsi[WS_ROWTOK + r] = -1;
    unsigned short* zr = (unsigned short*)((char*)wsi + WSB_ZROW);
    for (int i = t; i < H; i += 256) zr[i] = 0;
    __syncthreads();

    int e0a[8], e1a[8];
    #pragma unroll
    for (int j = 0; j < 8; j++) {
        int tok = t * 8 + j;
        const float* l = logits + tok * 8;
        float v0 = -1e30f; int i0 = 0;
        #pragma unroll
        for (int i = 0; i < 8; i++) { float v = l[i]; if (v > v0) { v0 = v; i0 = i; } }
        float v1 = -1e30f; int i1 = 0;
        #pragma unroll
        for (int i = 0; i < 8; i++) { if (i == i0) continue; float v = l[i]; if (v > v1) { v1 = v; i1 = i; } }
        float ex = __expf(v1 - v0);
        float inv = 1.f / (1.f + ex);
        wsf[WS_TOPKP + tok * 2] = inv;
        wsf[WS_TOPKP + tok * 2 + 1] = ex * inv;
        e0a[j] = i0; e1a[j] = i1;
        atomicAdd(&cnt[i0], 1);
        atomicAdd(&cnt[i1], 1);
    }
    __syncthreads();
    if (t == 0) {
        int acc = 0;
        for (int e = 0; e < 8; e++) { base[e] = acc; acc += (cnt[e] + 127) & ~127; }
        base[8] = acc;
        for (int e = 0; e < 9; e++) wsi[WS_OFF + e] = base[e];
    }
    __syncthreads();
    for (int tt = t; tt < MAXT; tt += 256) {
        int rb = tt * 128, ex = 0;
        for (int e = 0; e < 8; e++)
            if (rb >= base[e] && rb < base[e + 1]) ex = e;
        wsi[WS_TEXP + tt] = ex;
    }
    #pragma unroll
    for (int j = 0; j < 8; j++) {
        int tok = t * 8 + j;
        int ee[2] = {e0a[j], e1a[j]};
        #pragma unroll
        for (int k = 0; k < 2; k++) {
            int e = ee[k];
            int slot = atomicAdd(&fill[e], 1);
            int r = base[e] + slot;
            wsi[WS_ROWTOK + r] = tok;
            wsi[WS_TOKROW + tok * 2 + k] = r;
        }
    }
}

// ---------------- fc1 (128x128, BK=32, counted-vmcnt pipeline) + SwiGLU ----------------
// blocks >= FC1_BLKS pack w2 (overlapped; consumed only by fc2), gl2lds-staged like pre.
// pw2 layout: block ((e*8+ht)*64)+k0i holds [kg:4][n:128][kk:8], col=ht*128+n
__global__ __launch_bounds__(256, 4) void fc1_kernel(
    const unsigned short* __restrict__ hsb, const unsigned short* __restrict__ pw1,
    const int* __restrict__ wsi, const unsigned short* __restrict__ zrow,
    unsigned short* __restrict__ act,
    const float* __restrict__ w2, unsigned short* __restrict__ pw2) {
    __shared__ __align__(16) unsigned short SM[32 * 512];   // 32 KB: A0|B0|A1|B1 (or fp32 w2 tile)
    const int t = threadIdx.x;

    if (blockIdx.x >= FC1_BLKS) {
        // ---- w2 pack path ([k:32][c:256] fp32 tile via gl2lds) ----
        float* Lf = (float*)SM;
        int b = (int)blockIdx.x - FC1_BLKS;
        int cs = b & 3, k0i = (b >> 2) & 63, e = b >> 8;
        const float* src = w2 + (size_t)e * I * H + (size_t)(k0i * 32) * H + cs * 256;
        #pragma unroll
        for (int i = 0; i < 8; i++) {
            int c = t + i * 256;
            int row = c >> 6, col4 = (c & 63) * 4;
            gl2lds16(src + (size_t)row * H + col4, &Lf[c * 4]);
        }
        __syncthreads();
        #pragma unroll
        for (int i = 0; i < 4; i++) {
            int cidx = t + i * 256;
            int n = cidx & 127, kg = (cidx >> 7) & 3, h1 = cidx >> 9;
            int x = h1 * 128 + n;
            s16x8 s;
            #pragma unroll
            for (int kk = 0; kk < 8; kk++) s[kk] = f2bf(Lf[(kg * 8 + kk) * 256 + x]);
            int ht = cs * 2 + h1;
            *(s16x8*)(pw2 + ((size_t)(e * 8 + ht) * 64 + k0i) * 4096 + (kg * 128 + n) * 8) = s;
        }
        return;
    }

    // ---- fc1 path ----
    unsigned short* A0 = SM;            // [kg:4][m:128][8]
    unsigned short* B0 = SM + 4096;     // [kg:4][n:128][8]
    unsigned short* A1 = SM + 8192;
    unsigned short* B1 = SM + 12288;
    const int ct = blockIdx.x & 31, rt = blockIdx.x >> 5;
    const int rowb = rt * 128;
    if (rowb >= wsi[WS_OFF + 8]) return;
    const int e = wsi[WS_TEXP + rt];
    const unsigned short* pb = pw1 + (size_t)((e * 32 + ct) * 32) * 4096;

    const int m = t & 127;
    const int tok = wsi[WS_ROWTOK + rowb + m];
    const unsigned short* rp = (tok >= 0) ? (hsb + (size_t)tok * H) : zrow;
    const int kga = t >> 7;

    const int lane = t & 63, w = t >> 6, wr = w >> 1, wc = w & 1;
    const int q = lane >> 4, l16 = lane & 15;

    f32x4 zero = {0.f, 0.f, 0.f, 0.f};
    f32x4 acc[4][4];
    #pragma unroll
    for (int mi = 0; mi < 4; mi++)
        #pragma unroll
        for (int ni = 0; ni < 4; ni++) acc[mi][ni] = zero;

    #define FC1_STAGE(k0i, Ab, Bb)                                             \
        do {                                                                   \
            const int k0_ = (k0i) * 32;                                        \
            gl2lds16(rp + k0_ + kga * 8, &(Ab)[t * 8]);                        \
            gl2lds16(rp + k0_ + (kga + 2) * 8, &(Ab)[(t + 256) * 8]);          \
            const unsigned short* ps_ = pb + (size_t)(k0i) * 4096;             \
            gl2lds16(ps_ + t * 8, &(Bb)[t * 8]);                               \
            gl2lds16(ps_ + (t + 256) * 8, &(Bb)[(t + 256) * 8]);               \
        } while (0)

    #define FC1_COMPUTE(Ab, Bb)                                                \
        do {                                                                   \
            s16x8 af[4], bf[4];                                                \
            _Pragma("unroll")                                                  \
            for (int mi = 0; mi < 4; mi++)                                     \
                af[mi] = *(const s16x8*)&(Ab)[(q * 128 + wr * 64 + mi * 16 + l16) * 8]; \
            _Pragma("unroll")                                                  \
            for (int ni = 0; ni < 4; ni++)                                     \
                bf[ni] = *(const s16x8*)&(Bb)[(q * 128 + wc * 64 + ni * 16 + l16) * 8]; \
            _Pragma("unroll")                                                  \
            for (int mi = 0; mi < 4; mi++)                                     \
                _Pragma("unroll")                                              \
                for (int ni = 0; ni < 4; ni++)                                 \
                    acc[mi][ni] = MFMA16(af[mi], bf[ni], acc[mi][ni]);         \
        } while (0)

    FC1_STAGE(0, A0, B0);
    FC1_STAGE(1, A1, B1);
    for (int k0i = 0; k0i < 30; k0i += 2) {
        VM_WAIT4;                          // S(k) done; S(k+1) stays in flight
        BARRIER;
        FC1_COMPUTE(A0, B0);
        BARRIER;
        FC1_STAGE(k0i + 2, A0, B0);
        VM_WAIT4;
        BARRIER;
        FC1_COMPUTE(A1, B1);
        BARRIER;
        FC1_STAGE(k0i + 3, A1, B1);
    }
    VM_WAIT4;                              // S30 done (S31 in flight)
    BARRIER;
    FC1_COMPUTE(A0, B0);
    BARRIER;
    VM_WAIT0;                              // S31 done
    BARRIER;
    FC1_COMPUTE(A1, B1);

    // epilogue: wave cols = 32 proj + 32 gate (ni 0,1 = proj; ni 2,3 = matching gate)
    #pragma unroll
    for (int mi = 0; mi < 4; mi++)
        #pragma unroll
        for (int r = 0; r < 4; r++) {
            int row = rowb + wr * 64 + mi * 16 + q * 4 + r;
            #pragma unroll
            for (int ni = 0; ni < 2; ni++) {
                int col = ct * 64 + wc * 32 + ni * 16 + l16;
                float p = acc[mi][ni][r], g = acc[mi][ni + 2][r];
                float val = p * g / (1.f + __expf(-p));
                act[(size_t)row * I + col] = (unsigned short)f2bf(val);
            }
        }
}

// ---------------- fc2 (128x128, BK=32, K-split x2, counted-vmcnt pipeline) -> eo partials ----------------
__global__ __launch_bounds__(256, 4) void fc2_kernel(
    const unsigned short* __restrict__ act, const unsigned short* __restrict__ pw2,
    const int* __restrict__ wsi, float* __restrict__ eo) {
    __shared__ __align__(16) unsigned short SM[32 * 512];   // A0|B0|A1|B1
    unsigned short* A0 = SM;
    unsigned short* B0 = SM + 4096;
    unsigned short* A1 = SM + 8192;
    unsigned short* B1 = SM + 12288;
    const int t = threadIdx.x;
    const int ht = blockIdx.x, rt = blockIdx.y, ks = blockIdx.z;
    const int rowb = rt * 128;
    if (rowb >= wsi[WS_OFF + 8]) return;
    const int e = wsi[WS_TEXP + rt];
    const unsigned short* pb = pw2 + (size_t)((e * 8 + ht) * 64) * 4096;

    const int m = t & 127;
    const unsigned short* rp = act + (size_t)(rowb + m) * I;
    const int kga = t >> 7;

    const int lane = t & 63, w = t >> 6, wr = w >> 1, wc = w & 1;
    const int q = lane >> 4, l16 = lane & 15;

    f32x4 zero = {0.f, 0.f, 0.f, 0.f};
    f32x4 acc[4][4];
    #pragma unroll
    for (int mi = 0; mi < 4; mi++)
        #pragma unroll
        for (int ni = 0; ni < 4; ni++) acc[mi][ni] = zero;

    #define FC2_STAGE(k0i, Ab, Bb)                                             \
        do {                                                                   \
            const int k0_ = (k0i) * 32;                                        \
            gl2lds16(rp + k0_ + kga * 8, &(Ab)[t * 8]);                        \
            gl2lds16(rp + k0_ + (kga + 2) * 8, &(Ab)[(t + 256) * 8]);          \
            const unsigned short* ps_ = pb + (size_t)(k0i) * 4096;             \
            gl2lds16(ps_ + t * 8, &(Bb)[t * 8]);                               \
            gl2lds16(ps_ + (t + 256) * 8, &(Bb)[(t + 256) * 8]);               \
        } while (0)

    #define FC2_COMPUTE(Ab, Bb)                                                \
        do {                                                                   \
            s16x8 af[4], bf[4];                                                \
            _Pragma("unroll")                                                  \
            for (int mi = 0; mi < 4; mi++)                                     \
                af[mi] = *(const s16x8*)&(Ab)[(q * 128 + wr * 64 + mi * 16 + l16) * 8]; \
            _Pragma("unroll")                                                  \
            for (int ni = 0; ni < 4; ni++)                                     \
                bf[ni] = *(const s16x8*)&(Bb)[(q * 128 + wc * 64 + ni * 16 + l16) * 8]; \
            _Pragma("unroll")                                                  \
            for (int mi = 0; mi < 4; mi++)                                     \
                _Pragma("unroll")                                              \
                for (int ni = 0; ni < 4; ni++)                                 \
                    acc[mi][ni] = MFMA16(af[mi], bf[ni], acc[mi][ni]);         \
        } while (0)

    const int kb = ks * 32;
    FC2_STAGE(kb, A0, B0);
    FC2_STAGE(kb + 1, A1, B1);
    for (int j = 0; j < 30; j += 2) {
        VM_WAIT4;
        BARRIER;
        FC2_COMPUTE(A0, B0);
        BARRIER;
        FC2_STAGE(kb + j + 2, A0, B0);
        VM_WAIT4;
        BARRIER;
        FC2_COMPUTE(A1, B1);
        BARRIER;
        FC2_STAGE(kb + j + 3, A1, B1);
    }
    VM_WAIT4;
    BARRIER;
    FC2_COMPUTE(A0, B0);
    BARRIER;
    VM_WAIT0;
    BARRIER;
    FC2_COMPUTE(A1, B1);

    float* ed = eo + (size_t)ks * RCAP * H;
    #pragma unroll
    for (int mi = 0; mi < 4; mi++)
        #pragma unroll
        for (int r = 0; r < 4; r++) {
            int row = rowb + wr * 64 + mi * 16 + q * 4 + r;
            #pragma unroll
            for (int ni = 0; ni < 4; ni++) {
                int col = ht * 128 + wc * 64 + ni * 16 + l16;
                ed[(size_t)row * H + col] = acc[mi][ni][r];
            }
        }
}

// ---------------- combine: out[tok] = s0*(eo0[r0]+eo1[r0]) + s1*(eo0[r1]+eo1[r1]) ----------------
__global__ __launch_bounds__(256) void combine_kernel(
    const float* __restrict__ eo, const int* __restrict__ wsi,
    const float* __restrict__ wsf, float* __restrict__ out) {
    const int tok = blockIdx.x;
    const int r0 = wsi[WS_TOKROW + tok * 2], r1 = wsi[WS_TOKROW + tok * 2 + 1];
    const float s0 = wsf[WS_TOPKP + tok * 2], s1 = wsf[WS_TOPKP + tok * 2 + 1];
    const float* a0 = eo + (size_t)r0 * H;
    const float* a1 = eo + (size_t)RCAP * H + (size_t)r0 * H;
    const float* b0 = eo + (size_t)r1 * H;
    const float* b1 = eo + (size_t)RCAP * H + (size_t)r1 * H;
    const int c = threadIdx.x * 4;
    f32x4 va0 = *(const f32x4*)(a0 + c), va1 = *(const f32x4*)(a1 + c);
    f32x4 vb0 = *(const f32x4*)(b0 + c), vb1 = *(const f32x4*)(b1 + c);
    f32x4 r;
    #pragma unroll
    for (int i = 0; i < 4; i++) r[i] = s0 * (va0[i] + va1[i]) + s1 * (vb0[i] + vb1[i]);
    *(f32x4*)(out + (size_t)tok * H + c) = r;
}

extern "C" void kernel_launch(void* const* d_in, const int* in_sizes, int n_in,
                              void* d_out, int out_size, void* d_ws, size_t ws_size,
                              hipStream_t stream) {
    const float* hs     = (const float*)d_in[0];
    const float* logits = (const float*)d_in[1];
    const float* w1     = (const float*)d_in[2];
    const float* w2     = (const float*)d_in[3];
    float* out = (float*)d_out;
    int* wsi = (int*)d_ws;
    float* wsf = (float*)d_ws;
    unsigned short* zrow = (unsigned short*)((char*)d_ws + WSB_ZROW);
    unsigned short* hsb  = (unsigned short*)((char*)d_ws + WSB_HSB);
    unsigned short* act  = (unsigned short*)((char*)d_ws + WSB_ACT);
    unsigned short* pw1  = (unsigned short*)((char*)d_ws + WSB_PW1);
    unsigned short* pw2  = (unsigned short*)((char*)d_ws + WSB_PW2);
    float* eo = (float*)((char*)d_ws + WSB_PW1);   // aliases pw1 (consumed by fc1 before fc2 runs)

    pre_kernel<<<W1T_BLKS + 1 + HSB_BLKS, 256, 0, stream>>>(logits, wsi, wsf, hs, hsb, w1, pw1);
    fc1_kernel<<<FC1_BLKS + W2T_BLKS, 256, 0, stream>>>(hsb, pw1, wsi, zrow, act, w2, pw2);
    fc2_kernel<<<dim3(8, MAXT, 2), 256, 0, stream>>>(act, pw2, wsi, eo);
    combine_kernel<<<T, 256, 0, stream>>>(eo, wsi, wsf, out);
}

// Round 6
// 352.592 us; speedup vs baseline: 1.0857x; 1.0035x over previous
//
#include <hip/hip_runtime.h>
#include <hip/hip_bf16.h>

// Problem constants (AriaExperts): tokens=2048, hidden=1024, inter=2048, E=8, topk=2
constexpr int T = 2048;
constexpr int H = 1024;
constexpr int I = 2048;
constexpr int N2 = 2 * I;      // fc1 weight cols (proj|gate)
constexpr int RCAP = 5120;     // padded row capacity
constexpr int MAXT = 40;       // max 128-row tiles

// ws int-offset map (ints)
constexpr int WS_OFF = 16;                 // [16,25) expert row offsets (padded)
constexpr int WS_TEXP = 32;                // [32,72) tile -> expert
constexpr int WS_TOPKP = 4256;             // [4256,8352) token scales (float)
constexpr int WS_ROWTOK = 8352;            // [8352,13472) row -> token
constexpr int WS_TOKROW = 13472;           // [13472,17568) token -> 2 rows
// ws byte offsets
constexpr size_t WSB_ZROW = 114688;        // bf16 zero row, H elements
constexpr size_t WSB_HSB  = 131072;        // bf16 hidden_states [T][H] (4 MB)
constexpr size_t WSB_ACT  = 8u << 20;      // bf16 act [RCAP][I] (20 MB)
constexpr size_t WSB_PW1  = 32u << 20;     // packed bf16 w1 (64 MB); reused as eo[2][RCAP][H] fp32 (40 MB)
constexpr size_t WSB_PW2  = 96u << 20;     // packed bf16 w2 (32 MB) -> 128 MB ws

// grids
constexpr int W1T_BLKS = 8 * 32 * 16;      // e * k0i * colslab(256)  = 4096
constexpr int W2T_BLKS = 8 * 64 * 4;       // e * k0i * colslab(256)  = 2048
constexpr int HSB_BLKS = T * H / 2048;     // 1024
constexpr int FC1_BLKS = 32 * MAXT;        // 1280

typedef __attribute__((ext_vector_type(4))) float f32x4;
typedef __attribute__((ext_vector_type(8))) short s16x8;

__device__ __forceinline__ short f2bf(float f) {
    unsigned u = __float_as_uint(f);
    u += 0x7FFFu + ((u >> 16) & 1u);   // round-to-nearest-even
    return (short)(u >> 16);
}

#define MFMA16(a, b, c) __builtin_amdgcn_mfma_f32_16x16x32_bf16(a, b, c, 0, 0, 0)

__device__ __forceinline__ void gl2lds16(const void* g, void* l) {
    __builtin_amdgcn_global_load_lds(
        (const __attribute__((address_space(1))) void*)g,
        (__attribute__((address_space(3))) void*)l, 16, 0, 0);
}

// counted-vmcnt sync primitives (T4): never drain vmcnt to 0 inside the K-loop.
// 3-stage pipeline: steady-state keeps 2 stages (8 gl2lds) in flight -> ~2 phases
// of latency coverage (~600-700cy), matching HBM load latency.
#define VM_WAIT8 asm volatile("s_waitcnt vmcnt(8)" ::: "memory")
#define VM_WAIT4 asm volatile("s_waitcnt vmcnt(4)" ::: "memory")
#define VM_WAIT0 asm volatile("s_waitcnt vmcnt(0)" ::: "memory")
#define BARRIER                                     \
    do {                                            \
        asm volatile("" ::: "memory");              \
        __builtin_amdgcn_s_barrier();               \
        asm volatile("" ::: "memory");              \
    } while (0)

// ---------------- pre: w1-pack (blocks [0,W1T)), routing (block W1T), hs->bf16 (rest) ----------------
// w1-pack: phase 1 stages a [k:32][c:256] fp32 tile via global_load_lds; phase 2 gathers
// 8 k's per output chunk from LDS, converts to bf16, writes 16B packed chunks.
// pw1 layout: block ((e*32+ct)*32)+k0i holds [kg:4][n:128][kk:8];
//   col = (sub&1 ? I : 0) + ct*64 + (sub>>1)*32 + (n&31), sub=n>>5
__global__ __launch_bounds__(256) void pre_kernel(const float* __restrict__ logits,
                                                  int* __restrict__ wsi,
                                                  float* __restrict__ wsf,
                                                  const float* __restrict__ hs,
                                                  unsigned short* __restrict__ hsb,
                                                  const float* __restrict__ w1,
                                                  unsigned short* __restrict__ pw1) {
    __shared__ __align__(16) float Lf[32 * 256];   // 32 KB
    const int t = threadIdx.x;

    if (blockIdx.x < W1T_BLKS) {
        int b = blockIdx.x;
        int cs = b & 15, k0i = (b >> 4) & 31, e = b >> 9;
        const float* src = w1 + (size_t)e * H * N2 + (size_t)(k0i * 32) * N2 + cs * 256;
        #pragma unroll
        for (int i = 0; i < 8; i++) {
            int c = t + i * 256;                 // 2048 x 16B chunks
            int row = c >> 6, col4 = (c & 63) * 4;
            gl2lds16(src + (size_t)row * N2 + col4, &Lf[c * 4]);
        }
        __syncthreads();
        int gatebit = cs >> 3, csl = cs & 7;
        #pragma unroll
        for (int i = 0; i < 4; i++) {
            int cidx = t + i * 256;              // 1024 output chunks
            int within = cidx & 31, subh = (cidx >> 5) & 1;
            int kg = (cidx >> 6) & 3, ctp = cidx >> 8;
            int x = ctp * 64 + subh * 32 + within;           // LDS col
            s16x8 s;
            #pragma unroll
            for (int kk = 0; kk < 8; kk++) s[kk] = f2bf(Lf[(kg * 8 + kk) * 256 + x]);
            int n = gatebit * 32 + subh * 64 + within;       // packed n
            int ct = csl * 4 + ctp;
            *(s16x8*)(pw1 + ((size_t)(e * 32 + ct) * 32 + k0i) * 4096 + (kg * 128 + n) * 8) = s;
        }
        return;
    }
    if (blockIdx.x > W1T_BLKS) {
        // ---- hs -> bf16, streaming ----
        int i = (((int)blockIdx.x - W1T_BLKS - 1) * 256 + t) * 8;
        f32x4 a = *(const f32x4*)(hs + i);
        f32x4 b = *(const f32x4*)(hs + i + 4);
        s16x8 s = {f2bf(a[0]), f2bf(a[1]), f2bf(a[2]), f2bf(a[3]),
                   f2bf(b[0]), f2bf(b[1]), f2bf(b[2]), f2bf(b[3])};
        *(s16x8*)(hsb + i) = s;
        return;
    }

    // ---- routing (single block) ----
    int* cnt  = (int*)Lf;
    int* base = cnt + 8;
    int* fill = base + 9;
    if (t < 8) { cnt[t] = 0; fill[t] = 0; }
    for (int r = t; r < RCAP; r += 256) wsi[WS_ROWTOK + r] = -1;
    unsigned short* zr = (unsigned short*)((char*)wsi + WSB_ZROW);
    for (int i = t; i < H; i += 256) zr[i] = 0;
    __syncthreads();

    int e0a[8], e1a[8];
    #pragma unroll
    for (int j = 0; j < 8; j++) {
        int tok = t * 8 + j;
        const float* l = logits + tok * 8;
        float v0 = -1e30f; int i0 = 0;
        #pragma unroll
        for (int i = 0; i < 8; i++) { float v = l[i]; if (v > v0) { v0 = v; i0 = i; } }
        float v1 = -1e30f; int i1 = 0;
        #pragma unroll
        for (int i = 0; i < 8; i++) { if (i == i0) continue; float v = l[i]; if (v > v1) { v1 = v; i1 = i; } }
        float ex = __expf(v1 - v0);
        float inv = 1.f / (1.f + ex);
        wsf[WS_TOPKP + tok * 2] = inv;
        wsf[WS_TOPKP + tok * 2 + 1] = ex * inv;
        e0a[j] = i0; e1a[j] = i1;
        atomicAdd(&cnt[i0], 1);
        atomicAdd(&cnt[i1], 1);
    }
    __syncthreads();
    if (t == 0) {
        int acc = 0;
        for (int e = 0; e < 8; e++) { base[e] = acc; acc += (cnt[e] + 127) & ~127; }
        base[8] = acc;
        for (int e = 0; e < 9; e++) wsi[WS_OFF + e] = base[e];
    }
    __syncthreads();
    for (int tt = t; tt < MAXT; tt += 256) {
        int rb = tt * 128, ex = 0;
        for (int e = 0; e < 8; e++)
            if (rb >= base[e] && rb < base[e + 1]) ex = e;
        wsi[WS_TEXP + tt] = ex;
    }
    #pragma unroll
    for (int j = 0; j < 8; j++) {
        int tok = t * 8 + j;
        int ee[2] = {e0a[j], e1a[j]};
        #pragma unroll
        for (int k = 0; k < 2; k++) {
            int e = ee[k];
            int slot = atomicAdd(&fill[e], 1);
            int r = base[e] + slot;
            wsi[WS_ROWTOK + r] = tok;
            wsi[WS_TOKROW + tok * 2 + k] = r;
        }
    }
}

// ---------------- fc1 (128x128, BK=32, 3-stage counted-vmcnt pipeline) + SwiGLU ----------------
// blocks >= FC1_BLKS pack w2 (overlapped; consumed only by fc2), gl2lds-staged.
// pw2 layout: block ((e*8+ht)*64)+k0i holds [kg:4][n:128][kk:8], col=ht*128+n
__global__ __launch_bounds__(256, 3) void fc1_kernel(
    const unsigned short* __restrict__ hsb, const unsigned short* __restrict__ pw1,
    const int* __restrict__ wsi, const unsigned short* __restrict__ zrow,
    unsigned short* __restrict__ act,
    const float* __restrict__ w2, unsigned short* __restrict__ pw2) {
    __shared__ __align__(16) unsigned short SM[3 * 8192];   // 48 KB: 3x(A|B) (or fp32 w2 tile)
    const int t = threadIdx.x;

    if (blockIdx.x >= FC1_BLKS) {
        // ---- w2 pack path ([k:32][c:256] fp32 tile via gl2lds) ----
        float* Lf = (float*)SM;
        int b = (int)blockIdx.x - FC1_BLKS;
        int cs = b & 3, k0i = (b >> 2) & 63, e = b >> 8;
        const float* src = w2 + (size_t)e * I * H + (size_t)(k0i * 32) * H + cs * 256;
        #pragma unroll
        for (int i = 0; i < 8; i++) {
            int c = t + i * 256;
            int row = c >> 6, col4 = (c & 63) * 4;
            gl2lds16(src + (size_t)row * H + col4, &Lf[c * 4]);
        }
        __syncthreads();
        #pragma unroll
        for (int i = 0; i < 4; i++) {
            int cidx = t + i * 256;
            int n = cidx & 127, kg = (cidx >> 7) & 3, h1 = cidx >> 9;
            int x = h1 * 128 + n;
            s16x8 s;
            #pragma unroll
            for (int kk = 0; kk < 8; kk++) s[kk] = f2bf(Lf[(kg * 8 + kk) * 256 + x]);
            int ht = cs * 2 + h1;
            *(s16x8*)(pw2 + ((size_t)(e * 8 + ht) * 64 + k0i) * 4096 + (kg * 128 + n) * 8) = s;
        }
        return;
    }

    // ---- fc1 path ----
    unsigned short* S0 = SM;            // [A: [kg:4][m:128][8] | B: [kg:4][n:128][8]]
    unsigned short* S1 = SM + 8192;
    unsigned short* S2 = SM + 16384;
    const int ct = blockIdx.x & 31, rt = blockIdx.x >> 5;
    const int rowb = rt * 128;
    if (rowb >= wsi[WS_OFF + 8]) return;
    const int e = wsi[WS_TEXP + rt];
    const unsigned short* pb = pw1 + (size_t)((e * 32 + ct) * 32) * 4096;

    const int m = t & 127;
    const int tok = wsi[WS_ROWTOK + rowb + m];
    const unsigned short* rp = (tok >= 0) ? (hsb + (size_t)tok * H) : zrow;
    const int kga = t >> 7;

    const int lane = t & 63, w = t >> 6, wr = w >> 1, wc = w & 1;
    const int q = lane >> 4, l16 = lane & 15;

    f32x4 zero = {0.f, 0.f, 0.f, 0.f};
    f32x4 acc[4][4];
    #pragma unroll
    for (int mi = 0; mi < 4; mi++)
        #pragma unroll
        for (int ni = 0; ni < 4; ni++) acc[mi][ni] = zero;

    #define FC1_STAGE(k0i, Sb)                                                 \
        do {                                                                   \
            const int k0_ = (k0i) * 32;                                        \
            gl2lds16(rp + k0_ + kga * 8, &(Sb)[t * 8]);                        \
            gl2lds16(rp + k0_ + (kga + 2) * 8, &(Sb)[(t + 256) * 8]);          \
            const unsigned short* ps_ = pb + (size_t)(k0i) * 4096;             \
            gl2lds16(ps_ + t * 8, &(Sb)[4096 + t * 8]);                        \
            gl2lds16(ps_ + (t + 256) * 8, &(Sb)[4096 + (t + 256) * 8]);        \
        } while (0)

    #define FC1_COMPUTE(Sb)                                                    \
        do {                                                                   \
            s16x8 af[4], bf[4];                                                \
            _Pragma("unroll")                                                  \
            for (int mi = 0; mi < 4; mi++)                                     \
                af[mi] = *(const s16x8*)&(Sb)[(q * 128 + wr * 64 + mi * 16 + l16) * 8]; \
            _Pragma("unroll")                                                  \
            for (int ni = 0; ni < 4; ni++)                                     \
                bf[ni] = *(const s16x8*)&(Sb)[4096 + (q * 128 + wc * 64 + ni * 16 + l16) * 8]; \
            __builtin_amdgcn_s_setprio(1);                                     \
            _Pragma("unroll")                                                  \
            for (int mi = 0; mi < 4; mi++)                                     \
                _Pragma("unroll")                                              \
                for (int ni = 0; ni < 4; ni++)                                 \
                    acc[mi][ni] = MFMA16(af[mi], bf[ni], acc[mi][ni]);         \
            __builtin_amdgcn_s_setprio(0);                                     \
        } while (0)

    FC1_STAGE(0, S0);
    FC1_STAGE(1, S1);
    for (int j = 0; j < 30; j += 3) {
        FC1_STAGE(j + 2, S2);
        VM_WAIT8; BARRIER;                 // stage j done; j+1, j+2 in flight
        FC1_COMPUTE(S0);
        BARRIER;
        FC1_STAGE(j + 3, S0);
        VM_WAIT8; BARRIER;
        FC1_COMPUTE(S1);
        BARRIER;
        FC1_STAGE(j + 4, S1);
        VM_WAIT8; BARRIER;
        FC1_COMPUTE(S2);
        BARRIER;
    }
    VM_WAIT4; BARRIER;                     // stage 30 done (31 in flight)
    FC1_COMPUTE(S0);
    BARRIER;
    VM_WAIT0; BARRIER;                     // stage 31 done
    FC1_COMPUTE(S1);

    // epilogue: wave cols = 32 proj + 32 gate (ni 0,1 = proj; ni 2,3 = matching gate)
    #pragma unroll
    for (int mi = 0; mi < 4; mi++)
        #pragma unroll
        for (int r = 0; r < 4; r++) {
            int row = rowb + wr * 64 + mi * 16 + q * 4 + r;
            #pragma unroll
            for (int ni = 0; ni < 2; ni++) {
                int col = ct * 64 + wc * 32 + ni * 16 + l16;
                float p = acc[mi][ni][r], g = acc[mi][ni + 2][r];
                float val = p * g / (1.f + __expf(-p));
                act[(size_t)row * I + col] = (unsigned short)f2bf(val);
            }
        }
}

// ---------------- fc2 (128x128, BK=32, K-split x2, 3-stage counted-vmcnt pipeline) -> eo partials ----------------
__global__ __launch_bounds__(256, 3) void fc2_kernel(
    const unsigned short* __restrict__ act, const unsigned short* __restrict__ pw2,
    const int* __restrict__ wsi, float* __restrict__ eo) {
    __shared__ __align__(16) unsigned short SM[3 * 8192];   // 48 KB: 3x(A|B)
    unsigned short* S0 = SM;
    unsigned short* S1 = SM + 8192;
    unsigned short* S2 = SM + 16384;
    const int t = threadIdx.x;
    const int ht = blockIdx.x, rt = blockIdx.y, ks = blockIdx.z;
    const int rowb = rt * 128;
    if (rowb >= wsi[WS_OFF + 8]) return;
    const int e = wsi[WS_TEXP + rt];
    const unsigned short* pb = pw2 + (size_t)((e * 8 + ht) * 64) * 4096;

    const int m = t & 127;
    const unsigned short* rp = act + (size_t)(rowb + m) * I;
    const int kga = t >> 7;

    const int lane = t & 63, w = t >> 6, wr = w >> 1, wc = w & 1;
    const int q = lane >> 4, l16 = lane & 15;

    f32x4 zero = {0.f, 0.f, 0.f, 0.f};
    f32x4 acc[4][4];
    #pragma unroll
    for (int mi = 0; mi < 4; mi++)
        #pragma unroll
        for (int ni = 0; ni < 4; ni++) acc[mi][ni] = zero;

    #define FC2_STAGE(k0i, Sb)                                                 \
        do {                                                                   \
            const int k0_ = (k0i) * 32;                                        \
            gl2lds16(rp + k0_ + kga * 8, &(Sb)[t * 8]);                        \
            gl2lds16(rp + k0_ + (kga + 2) * 8, &(Sb)[(t + 256) * 8]);          \
            const unsigned short* ps_ = pb + (size_t)(k0i) * 4096;             \
            gl2lds16(ps_ + t * 8, &(Sb)[4096 + t * 8]);                        \
            gl2lds16(ps_ + (t + 256) * 8, &(Sb)[4096 + (t + 256) * 8]);        \
        } while (0)

    #define FC2_COMPUTE(Sb)                                                    \
        do {                                                                   \
            s16x8 af[4], bf[4];                                                \
            _Pragma("unroll")                                                  \
            for (int mi = 0; mi < 4; mi++)                                     \
                af[mi] = *(const s16x8*)&(Sb)[(q * 128 + wr * 64 + mi * 16 + l16) * 8]; \
            _Pragma("unroll")                                                  \
            for (int ni = 0; ni < 4; ni++)                                     \
                bf[ni] = *(const s16x8*)&(Sb)[4096 + (q * 128 + wc * 64 + ni * 16 + l16) * 8]; \
            __builtin_amdgcn_s_setprio(1);                                     \
            _Pragma("unroll")                                                  \
            for (int mi = 0; mi < 4; mi++)                                     \
                _Pragma("unroll")                                              \
                for (int ni = 0; ni < 4; ni++)                                 \
                    acc[mi][ni] = MFMA16(af[mi], bf[ni], acc[mi][ni]);         \
            __builtin_amdgcn_s_setprio(0);                                     \
        } while (0)

    const int kb = ks * 32;
    FC2_STAGE(kb, S0);
    FC2_STAGE(kb + 1, S1);
    for (int j = 0; j < 30; j += 3) {
        FC2_STAGE(kb + j + 2, S2);
        VM_WAIT8; BARRIER;
        FC2_COMPUTE(S0);
        BARRIER;
        FC2_STAGE(kb + j + 3, S0);
        VM_WAIT8; BARRIER;
        FC2_COMPUTE(S1);
        BARRIER;
        FC2_STAGE(kb + j + 4, S1);
        VM_WAIT8; BARRIER;
        FC2_COMPUTE(S2);
        BARRIER;
    }
    VM_WAIT4; BARRIER;
    FC2_COMPUTE(S0);
    BARRIER;
    VM_WAIT0; BARRIER;
    FC2_COMPUTE(S1);

    float* ed = eo + (size_t)ks * RCAP * H;
    #pragma unroll
    for (int mi = 0; mi < 4; mi++)
        #pragma unroll
        for (int r = 0; r < 4; r++) {
            int row = rowb + wr * 64 + mi * 16 + q * 4 + r;
            #pragma unroll
            for (int ni = 0; ni < 4; ni++) {
                int col = ht * 128 + wc * 64 + ni * 16 + l16;
                ed[(size_t)row * H + col] = acc[mi][ni][r];
            }
        }
}

// ---------------- combine: out[tok] = s0*(eo0[r0]+eo1[r0]) + s1*(eo0[r1]+eo1[r1]) ----------------
__global__ __launch_bounds__(256) void combine_kernel(
    const float* __restrict__ eo, const int* __restrict__ wsi,
    const float* __restrict__ wsf, float* __restrict__ out) {
    const int tok = blockIdx.x;
    const int r0 = wsi[WS_TOKROW + tok * 2], r1 = wsi[WS_TOKROW + tok * 2 + 1];
    const float s0 = wsf[WS_TOPKP + tok * 2], s1 = wsf[WS_TOPKP + tok * 2 + 1];
    const float* a0 = eo + (size_t)r0 * H;
    const float* a1 = eo + (size_t)RCAP * H + (size_t)r0 * H;
    const float* b0 = eo + (size_t)r1 * H;
    const float* b1 = eo + (size_t)RCAP * H + (size_t)r1 * H;
    const int c = threadIdx.x * 4;
    f32x4 va0 = *(const f32x4*)(a0 + c), va1 = *(const f32x4*)(a1 + c);
    f32x4 vb0 = *(const f32x4*)(b0 + c), vb1 = *(const f32x4*)(b1 + c);
    f32x4 r;
    #pragma unroll
    for (int i = 0; i < 4; i++) r[i] = s0 * (va0[i] + va1[i]) + s1 * (vb0[i] + vb1[i]);
    *(f32x4*)(out + (size_t)tok * H + c) = r;
}

extern "C" void kernel_launch(void* const* d_in, const int* in_sizes, int n_in,
                              void* d_out, int out_size, void* d_ws, size_t ws_size,
                              hipStream_t stream) {
    const float* hs     = (const float*)d_in[0];
    const float* logits = (const float*)d_in[1];
    const float* w1     = (const float*)d_in[2];
    const float* w2     = (const float*)d_in[3];
    float* out = (float*)d_out;
    int* wsi = (int*)d_ws;
    float* wsf = (float*)d_ws;
    unsigned short* zrow = (unsigned short*)((char*)d_ws + WSB_ZROW);
    unsigned short* hsb  = (unsigned short*)((char*)d_ws + WSB_HSB);
    unsigned short* act  = (unsigned short*)((char*)d_ws + WSB_ACT);
    unsigned short* pw1  = (unsigned short*)((char*)d_ws + WSB_PW1);
    unsigned short* pw2  = (unsigned short*)((char*)d_ws + WSB_PW2);
    float* eo = (float*)((char*)d_ws + WSB_PW1);   // aliases pw1 (consumed by fc1 before fc2 runs)

    pre_kernel<<<W1T_BLKS + 1 + HSB_BLKS, 256, 0, stream>>>(logits, wsi, wsf, hs, hsb, w1, pw1);
    fc1_kernel<<<FC1_BLKS + W2T_BLKS, 256, 0, stream>>>(hsb, pw1, wsi, zrow, act, w2, pw2);
    fc2_kernel<<<dim3(8, MAXT, 2), 256, 0, stream>>>(act, pw2, wsi, eo);
    combine_kernel<<<T, 256, 0, stream>>>(eo, wsi, wsf, out);
}